// Round 1
// baseline (1003.038 us; speedup 1.0000x reference)
//
#include <hip/hip_runtime.h>
#include <hip/hip_bf16.h>
#include <hip/hip_fp16.h>

#define N_TOK 8192
#define DDIM  1024
#define HDIM  4096
#define NEXP  8
#define NPAIR (N_TOK*2)

typedef unsigned short u16;
typedef _Float16 f16x8 __attribute__((ext_vector_type(8)));
typedef float    f32x4 __attribute__((ext_vector_type(4)));

__device__ inline u16 f2h_bits(float f){
  _Float16 h = (_Float16)f;
  return __builtin_bit_cast(unsigned short, h);
}

typedef const __attribute__((address_space(1))) void* gas1_cvp;
typedef       __attribute__((address_space(3))) void* gas3_vp;
__device__ inline void gload_lds16(const void* g, void* l){
  __builtin_amdgcn_global_load_lds((gas1_cvp)g, (gas3_vp)l, 16, 0, 0);
}

// ---------------- gating: logits -> top2 + softmax + counts ----------------
__global__ __launch_bounds__(256) void gate_kernel(
    const float* __restrict__ x, const float* __restrict__ gw, const float* __restrict__ gb,
    int* __restrict__ tok_e, float* __restrict__ tok_w, int* __restrict__ counts){
  int tok  = (int)((blockIdx.x*256u + threadIdx.x) >> 6);
  int lane = threadIdx.x & 63;
  if (tok >= N_TOK) return;
  const float* xr = x + (size_t)tok*DDIM;
  float acc[NEXP];
  #pragma unroll
  for (int e=0;e<NEXP;e++) acc[e]=0.f;
  for (int d=lane; d<DDIM; d+=64){
    float xv = xr[d];
    const float4* g4 = reinterpret_cast<const float4*>(gw + (size_t)d*NEXP);
    float4 a=g4[0], b=g4[1];
    acc[0]=fmaf(xv,a.x,acc[0]); acc[1]=fmaf(xv,a.y,acc[1]);
    acc[2]=fmaf(xv,a.z,acc[2]); acc[3]=fmaf(xv,a.w,acc[3]);
    acc[4]=fmaf(xv,b.x,acc[4]); acc[5]=fmaf(xv,b.y,acc[5]);
    acc[6]=fmaf(xv,b.z,acc[6]); acc[7]=fmaf(xv,b.w,acc[7]);
  }
  #pragma unroll
  for (int s=32;s>0;s>>=1)
    #pragma unroll
    for (int e=0;e<NEXP;e++) acc[e] += __shfl_xor(acc[e], s, 64);
  if (lane==0){
    #pragma unroll
    for (int e=0;e<NEXP;e++) acc[e]+=gb[e];
    int e0=0;
    #pragma unroll
    for (int e=1;e<NEXP;e++) if (acc[e]>acc[e0]) e0=e;   // strict >: ties -> lower idx (top_k)
    int e1 = (e0==0)?1:0;
    #pragma unroll
    for (int e=0;e<NEXP;e++) if (e!=e0 && acc[e]>acc[e1]) e1=e;
    float p1 = 1.f/(1.f+__expf(acc[e0]-acc[e1]));        // softmax over top2
    float p0 = 1.f-p1;
    tok_e[tok*2]=e0; tok_e[tok*2+1]=e1;
    tok_w[tok*2]=p0; tok_w[tok*2+1]=p1;
    atomicAdd(&counts[e0],1); atomicAdd(&counts[e1],1);
  }
}

__global__ void scan_kernel(const int* __restrict__ counts, int* __restrict__ offsets,
                            int* __restrict__ cursors){
  if (threadIdx.x==0){
    int s=0;
    for (int e=0;e<NEXP;e++){ offsets[e]=s; cursors[e]=s; s+=counts[e]; }
    offsets[NEXP]=s;
  }
}

// ------- build perm + gather token rows (fp32 -> fp16, expert-sorted) ------
__global__ __launch_bounds__(256) void build_gather_kernel(
    const float* __restrict__ x, const int* __restrict__ tok_e, const float* __restrict__ tok_w,
    int* __restrict__ cursors, int* __restrict__ perm, float* __restrict__ pairw,
    u16* __restrict__ xg){
  int p    = (int)((blockIdx.x*256u + threadIdx.x) >> 6);  // pair index
  int lane = threadIdx.x & 63;
  if (p >= NPAIR) return;
  int tok = p>>1;
  int pos = 0;
  if (lane==0){
    int e = tok_e[p];
    pos = atomicAdd(&cursors[e],1);
    perm[pos]=tok; pairw[pos]=tok_w[p];
  }
  pos = __shfl(pos, 0, 64);
  const float4* src = reinterpret_cast<const float4*>(x + (size_t)tok*DDIM);
  u16* dst = xg + (size_t)pos*DDIM;
  #pragma unroll
  for (int i=0;i<4;i++){
    float4 v = src[i*64+lane];
    ushort4 o;
    o.x=f2h_bits(v.x); o.y=f2h_bits(v.y); o.z=f2h_bits(v.z); o.w=f2h_bits(v.w);
    *reinterpret_cast<ushort4*>(dst + (size_t)(i*64+lane)*4) = o;
  }
}

// ------- transpose + convert: src fp32 [E][R][C] -> dst fp16 [E][C][R] -----
__global__ __launch_bounds__(256) void transpose_convert_kernel(
    const float* __restrict__ src, u16* __restrict__ dst, int R, int C){
  __shared__ float tile[64][65];
  int e = blockIdx.z;
  const float* s = src + (size_t)e*R*C;
  u16* d = dst + (size_t)e*R*C;
  int c0 = blockIdx.x*64, r0 = blockIdx.y*64;
  int t = threadIdx.x;
  int col = t & 63, rl = t >> 6;
  #pragma unroll
  for (int i=0;i<16;i++){
    int row = rl + i*4;
    tile[row][col] = s[(size_t)(r0+row)*C + (c0+col)];
  }
  __syncthreads();
  #pragma unroll
  for (int i=0;i<16;i++){
    int row = rl + i*4;  // index along C
    d[(size_t)(c0+row)*R + (r0+col)] = f2h_bits(tile[col][row]);
  }
}

__device__ inline float gelu_tanh(float x){
  float u = 0.7978845608028654f*(x + 0.044715f*x*x*x);
  u = fminf(fmaxf(u,-9.f),9.f);
  float e2 = __expf(2.f*u);
  return 0.5f*x*(1.f + (e2-1.f)/(e2+1.f));
}

// ---------------- segment GEMM: C[cnt x Nn] = A[cnt x Kd] * Bt^T -----------
// A: fp16 rows at Abase[off..], Bt: fp16 [E][Nn][Kd] (row = output col).
// EPI 0: h = gelu(acc + b1) -> Hout fp16.  EPI 1: atomicAdd(out[tok], w*(acc+b2)).
template<int EPI>
__global__ __launch_bounds__(256,2) void moe_gemm_kernel(
    const u16* __restrict__ Abase, const u16* __restrict__ Btbase,
    const float* __restrict__ bias,
    u16* __restrict__ Hout, float* __restrict__ Out,
    const int* __restrict__ offsets, const int* __restrict__ perm,
    const float* __restrict__ pairw, int Kd, int Nn){
  __shared__ __align__(16) u16 As[128*32];
  __shared__ __align__(16) u16 Bs[128*32];
  int e = blockIdx.z;
  int off = offsets[e], cnt = offsets[e+1]-off;
  int brow = blockIdx.y;
  if (brow*128 >= cnt) return;
  int bcol = blockIdx.x;
  int t = threadIdx.x;
  int lane = t & 63, wid = t >> 6;
  int wr = wid >> 1, wc = wid & 1;

  // staging: each thread owns two 16B slots of each 8KB tile
  int tb = t*16;                      // byte slot in [0,4096)
  int rowA0 = tb>>6, rowA1 = (tb+4096)>>6;   // 64B per row (BK=32 fp16)
  int koff  = (tb&63)>>1;                    // element offset in K
  int cm1 = cnt-1;
  const u16* aP0 = Abase + (size_t)(off + min(brow*128+rowA0, cm1))*Kd + koff;
  const u16* aP1 = Abase + (size_t)(off + min(brow*128+rowA1, cm1))*Kd + koff;
  const u16* Bt  = Btbase + (size_t)e*Nn*Kd;
  const u16* bP0 = Bt + (size_t)(bcol*128+rowA0)*Kd + koff;
  const u16* bP1 = Bt + (size_t)(bcol*128+rowA1)*Kd + koff;
  char* lA0 = (char*)As + tb;
  char* lA1 = (char*)As + 4096 + tb;
  char* lB0 = (char*)Bs + tb;
  char* lB1 = (char*)Bs + 4096 + tb;

  f32x4 acc[4][4] = {};
  int lr = lane & 15, lk = (lane>>4)*8;
  int aOff[4], bOff[4];
  #pragma unroll
  for (int i=0;i<4;i++){
    aOff[i] = (wr*64+i*16+lr)*32 + lk;
    bOff[i] = (wc*64+i*16+lr)*32 + lk;
  }

  int KT = Kd >> 5;
  gload_lds16(aP0,lA0); gload_lds16(aP1,lA1);
  gload_lds16(bP0,lB0); gload_lds16(bP1,lB1);
  aP0+=32; aP1+=32; bP0+=32; bP1+=32;

  for (int kt=0; kt<KT; ++kt){
    __syncthreads();                       // staged tile visible (drains vmcnt)
    f16x8 a[4], b[4];
    #pragma unroll
    for (int i=0;i<4;i++) a[i] = *reinterpret_cast<const f16x8*>(&As[aOff[i]]);
    #pragma unroll
    for (int i=0;i<4;i++) b[i] = *reinterpret_cast<const f16x8*>(&Bs[bOff[i]]);
    __syncthreads();                       // all reads done, LDS free
    if (kt+1 < KT){
      gload_lds16(aP0,lA0); gload_lds16(aP1,lA1);
      gload_lds16(bP0,lB0); gload_lds16(bP1,lB1);
      aP0+=32; aP1+=32; bP0+=32; bP1+=32;
    }
    #pragma unroll
    for (int fm=0;fm<4;fm++)
      #pragma unroll
      for (int fn=0;fn<4;fn++)
        acc[fm][fn] = __builtin_amdgcn_mfma_f32_16x16x32_f16(a[fm], b[fn], acc[fm][fn], 0,0,0);
  }

  // epilogue: C row = wr*64+fm*16+(lane>>4)*4+j, col = wc*64+fn*16+(lane&15)
  int lr4 = (lane>>4)*4, lc = lane&15;
  #pragma unroll
  for (int fm=0;fm<4;fm++){
    #pragma unroll
    for (int j=0;j<4;j++){
      int grow = brow*128 + wr*64 + fm*16 + lr4 + j;
      if (grow < cnt){
        int p = off + grow;
        if (EPI==0){
          size_t rbase = (size_t)p*Nn;
          #pragma unroll
          for (int fn=0;fn<4;fn++){
            int colg = bcol*128 + wc*64 + fn*16 + lc;
            float v = acc[fm][fn][j] + bias[e*Nn + colg];
            Hout[rbase + colg] = f2h_bits(gelu_tanh(v));
          }
        } else {
          int tok = perm[p]; float wv = pairw[p];
          size_t obase = (size_t)tok*Nn;
          #pragma unroll
          for (int fn=0;fn<4;fn++){
            int colg = bcol*128 + wc*64 + fn*16 + lc;
            atomicAdd(&Out[obase + colg], wv*(acc[fm][fn][j] + bias[e*Nn + colg]));
          }
        }
      }
    }
  }
}

extern "C" void kernel_launch(void* const* d_in, const int* in_sizes, int n_in,
                              void* d_out, int out_size, void* d_ws, size_t ws_size,
                              hipStream_t stream){
  const float* x  = (const float*)d_in[0];
  const float* gw = (const float*)d_in[1];
  const float* gb = (const float*)d_in[2];
  const float* w1 = (const float*)d_in[3];
  const float* b1 = (const float*)d_in[4];
  const float* w2 = (const float*)d_in[5];
  const float* b2 = (const float*)d_in[6];
  float* out = (float*)d_out;
  char* ws = (char*)d_ws;

  // workspace layout
  int*   counts  = (int*)(ws + 0);
  int*   offsets = (int*)(ws + 64);
  int*   cursors = (int*)(ws + 128);
  int*   tok_e   = (int*)(ws + 256);
  float* tok_w   = (float*)(ws + 256 + 1*65536);
  int*   perm    = (int*)(ws + 256 + 2*65536);
  float* pairw   = (float*)(ws + 256 + 3*65536);
  size_t base = 256 + 4*65536;                       // 262400 (256-aligned)
  u16* xg   = (u16*)(ws + base);                                     // 32 MiB
  u16* w1t  = (u16*)(ws + base + 33554432ull);                       // 64 MiB
  u16* w2t  = (u16*)(ws + base + 33554432ull + 67108864ull);         // 64 MiB
  u16* hbuf = (u16*)(ws + base + 33554432ull + 2*67108864ull);       // 128 MiB
  size_t need = base + 33554432ull + 2*67108864ull + 134217728ull;

  hipMemsetAsync(d_out, 0, (size_t)out_size*sizeof(float), stream);
  if (ws_size < need) return;   // graceful fail: zeros out
  hipMemsetAsync(ws, 0, 256, stream);

  gate_kernel<<<N_TOK/4, 256, 0, stream>>>(x, gw, gb, tok_e, tok_w, counts);
  scan_kernel<<<1, 64, 0, stream>>>(counts, offsets, cursors);
  build_gather_kernel<<<NPAIR/4, 256, 0, stream>>>(x, tok_e, tok_w, cursors, perm, pairw, xg);
  transpose_convert_kernel<<<dim3(HDIM/64, DDIM/64, NEXP), 256, 0, stream>>>(w1, w1t, DDIM, HDIM);
  transpose_convert_kernel<<<dim3(DDIM/64, HDIM/64, NEXP), 256, 0, stream>>>(w2, w2t, HDIM, DDIM);
  moe_gemm_kernel<0><<<dim3(HDIM/128, 64, NEXP), 256, 0, stream>>>(
      xg, w1t, b1, hbuf, nullptr, offsets, perm, pairw, DDIM, HDIM);
  moe_gemm_kernel<1><<<dim3(DDIM/128, 64, NEXP), 256, 0, stream>>>(
      hbuf, w2t, b2, nullptr, out, offsets, perm, pairw, HDIM, DDIM);
}

// Round 2
// 981.295 us; speedup vs baseline: 1.0222x; 1.0222x over previous
//
#include <hip/hip_runtime.h>
#include <hip/hip_bf16.h>
#include <hip/hip_fp16.h>

#define N_TOK 8192
#define DDIM  1024
#define HDIM  4096
#define NEXP  8
#define NPAIR (N_TOK*2)

typedef unsigned short u16;
typedef _Float16 f16x8 __attribute__((ext_vector_type(8)));
typedef float    f32x4 __attribute__((ext_vector_type(4)));
typedef unsigned short u16x8 __attribute__((ext_vector_type(8)));

__device__ inline u16 f2h_bits(float f){
  _Float16 h = (_Float16)f;
  return __builtin_bit_cast(unsigned short, h);
}

typedef const __attribute__((address_space(1))) void* gas1_cvp;
typedef       __attribute__((address_space(3))) void* gas3_vp;
__device__ inline void gload_lds16(const void* g, void* l){
  __builtin_amdgcn_global_load_lds((gas1_cvp)g, (gas3_vp)l, 16, 0, 0);
}

// ---------------- gating: logits -> top2 + softmax + counts ----------------
__global__ __launch_bounds__(256) void gate_kernel(
    const float* __restrict__ x, const float* __restrict__ gw, const float* __restrict__ gb,
    int* __restrict__ tok_e, float* __restrict__ tok_w, int* __restrict__ counts){
  int tok  = (int)((blockIdx.x*256u + threadIdx.x) >> 6);
  int lane = threadIdx.x & 63;
  if (tok >= N_TOK) return;
  const float* xr = x + (size_t)tok*DDIM;
  float acc[NEXP];
  #pragma unroll
  for (int e=0;e<NEXP;e++) acc[e]=0.f;
  for (int d=lane; d<DDIM; d+=64){
    float xv = xr[d];
    const float4* g4 = reinterpret_cast<const float4*>(gw + (size_t)d*NEXP);
    float4 a=g4[0], b=g4[1];
    acc[0]=fmaf(xv,a.x,acc[0]); acc[1]=fmaf(xv,a.y,acc[1]);
    acc[2]=fmaf(xv,a.z,acc[2]); acc[3]=fmaf(xv,a.w,acc[3]);
    acc[4]=fmaf(xv,b.x,acc[4]); acc[5]=fmaf(xv,b.y,acc[5]);
    acc[6]=fmaf(xv,b.z,acc[6]); acc[7]=fmaf(xv,b.w,acc[7]);
  }
  #pragma unroll
  for (int s=32;s>0;s>>=1)
    #pragma unroll
    for (int e=0;e<NEXP;e++) acc[e] += __shfl_xor(acc[e], s, 64);
  if (lane==0){
    #pragma unroll
    for (int e=0;e<NEXP;e++) acc[e]+=gb[e];
    int e0=0;
    #pragma unroll
    for (int e=1;e<NEXP;e++) if (acc[e]>acc[e0]) e0=e;   // strict >: ties -> lower idx (top_k)
    int e1 = (e0==0)?1:0;
    #pragma unroll
    for (int e=0;e<NEXP;e++) if (e!=e0 && acc[e]>acc[e1]) e1=e;
    float p1 = 1.f/(1.f+__expf(acc[e0]-acc[e1]));        // softmax over top2
    float p0 = 1.f-p1;
    tok_e[tok*2]=e0; tok_e[tok*2+1]=e1;
    tok_w[tok*2]=p0; tok_w[tok*2+1]=p1;
    atomicAdd(&counts[e0],1); atomicAdd(&counts[e1],1);
  }
}

__global__ void scan_kernel(const int* __restrict__ counts, int* __restrict__ offsets,
                            int* __restrict__ cursors){
  if (threadIdx.x==0){
    int s=0;
    for (int e=0;e<NEXP;e++){ offsets[e]=s; cursors[e]=s; s+=counts[e]; }
    offsets[NEXP]=s;
  }
}

// ------- build perm + gather token rows (fp32 -> fp16, expert-sorted) ------
__global__ __launch_bounds__(256) void build_gather_kernel(
    const float* __restrict__ x, const int* __restrict__ tok_e, const float* __restrict__ tok_w,
    int* __restrict__ cursors, int* __restrict__ perm, float* __restrict__ pairw,
    u16* __restrict__ xg){
  int p    = (int)((blockIdx.x*256u + threadIdx.x) >> 6);  // pair index
  int lane = threadIdx.x & 63;
  if (p >= NPAIR) return;
  int tok = p>>1;
  int pos = 0;
  if (lane==0){
    int e = tok_e[p];
    pos = atomicAdd(&cursors[e],1);
    perm[pos]=tok; pairw[pos]=tok_w[p];
  }
  pos = __shfl(pos, 0, 64);
  const float4* src = reinterpret_cast<const float4*>(x + (size_t)tok*DDIM);
  u16* dst = xg + (size_t)pos*DDIM;
  #pragma unroll
  for (int i=0;i<4;i++){
    float4 v = src[i*64+lane];
    ushort4 o;
    o.x=f2h_bits(v.x); o.y=f2h_bits(v.y); o.z=f2h_bits(v.z); o.w=f2h_bits(v.w);
    *reinterpret_cast<ushort4*>(dst + (size_t)(i*64+lane)*4) = o;
  }
}

// ------- transpose + convert: src fp32 [E][R][C] -> dst fp16 [E][C][R] -----
// 64x64 tiles; float4 reads, ushort8 (16B) writes.
__global__ __launch_bounds__(256) void transpose_convert_kernel(
    const float* __restrict__ src, u16* __restrict__ dst, int R, int C){
  __shared__ float tile[64][65];
  int e = blockIdx.z;
  const float* s = src + (size_t)e*R*C;
  u16* d = dst + (size_t)e*R*C;
  int c0 = blockIdx.x*64, r0 = blockIdx.y*64;
  int t = threadIdx.x;
  int col4 = (t & 15) * 4, rrow = t >> 4;      // 16 rows per pass
  #pragma unroll
  for (int i=0;i<4;i++){
    int row = i*16 + rrow;
    float4 v = *reinterpret_cast<const float4*>(&s[(size_t)(r0+row)*C + c0 + col4]);
    tile[row][col4+0]=v.x; tile[row][col4+1]=v.y;
    tile[row][col4+2]=v.z; tile[row][col4+3]=v.w;
  }
  __syncthreads();
  int cIdx0 = t >> 3, r8 = (t & 7) * 8;
  #pragma unroll
  for (int j=0;j<2;j++){
    int c = j*32 + cIdx0;
    u16x8 o;
    #pragma unroll
    for (int u=0;u<8;u++) o[u] = f2h_bits(tile[r8+u][c]);
    *reinterpret_cast<u16x8*>(&d[(size_t)(c0+c)*R + r0 + r8]) = o;
  }
}

__device__ inline float gelu_tanh(float x){
  float u = 0.7978845608028654f*(x + 0.044715f*x*x*x);
  u = fminf(fmaxf(u,-9.f),9.f);
  float e2 = __expf(2.f*u);
  return 0.5f*x*(1.f + (e2-1.f)/(e2+1.f));
}

// ---------------- segment GEMM: C[cnt x Nn] = A[cnt x Kd] * Bt^T -----------
// A: fp16 rows at Abase[off..], Bt: fp16 [E][Nn][Kd] (row = output col).
// EPI 0: h = gelu(acc + b1) -> Hout fp16.  EPI 1: atomicAdd(out[tok], w*(acc+b2)).
// 1D grid, expert-major; bijective XCD swizzle maps expert e -> XCD e.
// GEMM1 order: bcol outer, brow inner (A-panel 4MB L2-resident, B streamed once).
// GEMM2 order: 4-brow super-tile outer, bcol mid, brow inner (A 4MB resident).
template<int EPI>
__global__ __launch_bounds__(256,2) void moe_gemm_kernel(
    const u16* __restrict__ Abase, const u16* __restrict__ Btbase,
    const float* __restrict__ bias,
    u16* __restrict__ Hout, float* __restrict__ Out,
    const int* __restrict__ offsets, const int* __restrict__ perm,
    const float* __restrict__ pairw){
  constexpr int Kd = (EPI==0) ? DDIM : HDIM;
  constexpr int Nn = (EPI==0) ? HDIM : DDIM;
  constexpr int BR = 32;                 // max 4096 rows/expert
  constexpr int BC = Nn/128;
  constexpr int PER_E = BR*BC;
  constexpr int G = NEXP*PER_E;

  __shared__ __align__(16) u16 As[128*32];
  __shared__ __align__(16) u16 Bs[128*32];

  int bid = blockIdx.x;
  int lg = (bid & 7) * (G/8) + (bid >> 3);      // XCD-bijective swizzle (G%8==0)
  int e = lg / PER_E;
  int r = lg % PER_E;
  int brow, bcol;
  if (EPI==0){ bcol = r / BR; brow = r % BR; }
  else { int st = r >> 5; int q = r & 31; bcol = q >> 2; brow = st*4 + (q & 3); }

  int off = offsets[e], cnt = offsets[e+1]-off;
  if (brow*128 >= cnt) return;
  int t = threadIdx.x;
  int lane = t & 63, wid = t >> 6;
  int wr = wid >> 1, wc = wid & 1;

  // staging: each thread owns two 16B slots of each 8KB tile
  int tb = t*16;                      // byte slot in [0,4096)
  int rowA0 = tb>>6, rowA1 = (tb+4096)>>6;   // 64B per row (BK=32 fp16)
  int koff  = (tb&63)>>1;                    // element offset in K
  int cm1 = cnt-1;
  const u16* aP0 = Abase + (size_t)(off + min(brow*128+rowA0, cm1))*Kd + koff;
  const u16* aP1 = Abase + (size_t)(off + min(brow*128+rowA1, cm1))*Kd + koff;
  const u16* Bt  = Btbase + (size_t)e*Nn*Kd;
  const u16* bP0 = Bt + (size_t)(bcol*128+rowA0)*Kd + koff;
  const u16* bP1 = Bt + (size_t)(bcol*128+rowA1)*Kd + koff;
  char* lA0 = (char*)As + tb;
  char* lA1 = (char*)As + 4096 + tb;
  char* lB0 = (char*)Bs + tb;
  char* lB1 = (char*)Bs + 4096 + tb;

  f32x4 acc[4][4] = {};
  int lr = lane & 15, lk = (lane>>4)*8;
  int aOff[4], bOff[4];
  #pragma unroll
  for (int i=0;i<4;i++){
    aOff[i] = (wr*64+i*16+lr)*32 + lk;
    bOff[i] = (wc*64+i*16+lr)*32 + lk;
  }

  constexpr int KT = Kd >> 5;
  gload_lds16(aP0,lA0); gload_lds16(aP1,lA1);
  gload_lds16(bP0,lB0); gload_lds16(bP1,lB1);
  aP0+=32; aP1+=32; bP0+=32; bP1+=32;

  for (int kt=0; kt<KT; ++kt){
    __syncthreads();                       // staged tile visible (drains vmcnt)
    f16x8 a[4], b[4];
    #pragma unroll
    for (int i=0;i<4;i++) a[i] = *reinterpret_cast<const f16x8*>(&As[aOff[i]]);
    #pragma unroll
    for (int i=0;i<4;i++) b[i] = *reinterpret_cast<const f16x8*>(&Bs[bOff[i]]);
    __syncthreads();                       // all reads done, LDS free
    if (kt+1 < KT){
      gload_lds16(aP0,lA0); gload_lds16(aP1,lA1);
      gload_lds16(bP0,lB0); gload_lds16(bP1,lB1);
      aP0+=32; aP1+=32; bP0+=32; bP1+=32;
    }
    #pragma unroll
    for (int fm=0;fm<4;fm++)
      #pragma unroll
      for (int fn=0;fn<4;fn++)
        acc[fm][fn] = __builtin_amdgcn_mfma_f32_16x16x32_f16(a[fm], b[fn], acc[fm][fn], 0,0,0);
  }

  // epilogue: C row = wr*64+fm*16+(lane>>4)*4+j, col = wc*64+fn*16+(lane&15)
  int lr4 = (lane>>4)*4, lc = lane&15;
  #pragma unroll
  for (int fm=0;fm<4;fm++){
    #pragma unroll
    for (int j=0;j<4;j++){
      int grow = brow*128 + wr*64 + fm*16 + lr4 + j;
      if (grow < cnt){
        int p = off + grow;
        if (EPI==0){
          size_t rbase = (size_t)p*Nn;
          #pragma unroll
          for (int fn=0;fn<4;fn++){
            int colg = bcol*128 + wc*64 + fn*16 + lc;
            float v = acc[fm][fn][j] + bias[e*Nn + colg];
            Hout[rbase + colg] = f2h_bits(gelu_tanh(v));
          }
        } else {
          int tok = perm[p]; float wv = pairw[p];
          size_t obase = (size_t)tok*Nn;
          #pragma unroll
          for (int fn=0;fn<4;fn++){
            int colg = bcol*128 + wc*64 + fn*16 + lc;
            atomicAdd(&Out[obase + colg], wv*(acc[fm][fn][j] + bias[e*Nn + colg]));
          }
        }
      }
    }
  }
}

extern "C" void kernel_launch(void* const* d_in, const int* in_sizes, int n_in,
                              void* d_out, int out_size, void* d_ws, size_t ws_size,
                              hipStream_t stream){
  const float* x  = (const float*)d_in[0];
  const float* gw = (const float*)d_in[1];
  const float* gb = (const float*)d_in[2];
  const float* w1 = (const float*)d_in[3];
  const float* b1 = (const float*)d_in[4];
  const float* w2 = (const float*)d_in[5];
  const float* b2 = (const float*)d_in[6];
  float* out = (float*)d_out;
  char* ws = (char*)d_ws;

  // workspace layout
  int*   counts  = (int*)(ws + 0);
  int*   offsets = (int*)(ws + 64);
  int*   cursors = (int*)(ws + 128);
  int*   tok_e   = (int*)(ws + 256);
  float* tok_w   = (float*)(ws + 256 + 1*65536);
  int*   perm    = (int*)(ws + 256 + 2*65536);
  float* pairw   = (float*)(ws + 256 + 3*65536);
  size_t base = 256 + 4*65536;                       // 262400 (256-aligned)
  u16* xg   = (u16*)(ws + base);                                     // 32 MiB
  u16* w1t  = (u16*)(ws + base + 33554432ull);                       // 64 MiB
  u16* w2t  = (u16*)(ws + base + 33554432ull + 67108864ull);         // 64 MiB
  u16* hbuf = (u16*)(ws + base + 33554432ull + 2*67108864ull);       // 128 MiB
  size_t need = base + 33554432ull + 2*67108864ull + 134217728ull;

  hipMemsetAsync(d_out, 0, (size_t)out_size*sizeof(float), stream);
  if (ws_size < need) return;   // graceful fail: zeros out
  hipMemsetAsync(ws, 0, 256, stream);

  gate_kernel<<<N_TOK/4, 256, 0, stream>>>(x, gw, gb, tok_e, tok_w, counts);
  scan_kernel<<<1, 64, 0, stream>>>(counts, offsets, cursors);
  build_gather_kernel<<<NPAIR/4, 256, 0, stream>>>(x, tok_e, tok_w, cursors, perm, pairw, xg);
  transpose_convert_kernel<<<dim3(HDIM/64, DDIM/64, NEXP), 256, 0, stream>>>(w1, w1t, DDIM, HDIM);
  transpose_convert_kernel<<<dim3(DDIM/64, HDIM/64, NEXP), 256, 0, stream>>>(w2, w2t, HDIM, DDIM);
  moe_gemm_kernel<0><<<NEXP*32*(HDIM/128), 256, 0, stream>>>(
      xg, w1t, b1, hbuf, nullptr, offsets, perm, pairw);
  moe_gemm_kernel<1><<<NEXP*32*(DDIM/128), 256, 0, stream>>>(
      hbuf, w2t, b2, nullptr, out, offsets, perm, pairw);
}

// Round 3
// 753.880 us; speedup vs baseline: 1.3305x; 1.3017x over previous
//
#include <hip/hip_runtime.h>
#include <hip/hip_fp16.h>

#define N_TOK 8192
#define DDIM  1024
#define HDIM  4096
#define NEXP  8
#define NPAIR (N_TOK*2)

typedef unsigned short u16;
typedef _Float16 f16x8 __attribute__((ext_vector_type(8)));
typedef float    f32x4 __attribute__((ext_vector_type(4)));
typedef unsigned short u16x8 __attribute__((ext_vector_type(8)));

__device__ inline u16 f2h_bits(float f){
  _Float16 h = (_Float16)f;
  return __builtin_bit_cast(unsigned short, h);
}

typedef const __attribute__((address_space(1))) void* gas1_cvp;
typedef       __attribute__((address_space(3))) void* gas3_vp;
__device__ inline void gload_lds16(const void* g, void* l){
  __builtin_amdgcn_global_load_lds((gas1_cvp)g, (gas3_vp)l, 16, 0, 0);
}

// ---------------- gating: logits -> top2 + softmax (no atomics) ------------
__global__ __launch_bounds__(256) void gate_kernel(
    const float* __restrict__ x, const float* __restrict__ gw, const float* __restrict__ gb,
    int* __restrict__ tok_e, float* __restrict__ tok_w){
  int tok  = (int)((blockIdx.x*256u + threadIdx.x) >> 6);
  int lane = threadIdx.x & 63;
  if (tok >= N_TOK) return;
  const float* xr = x + (size_t)tok*DDIM;
  float acc[NEXP];
  #pragma unroll
  for (int e=0;e<NEXP;e++) acc[e]=0.f;
  for (int d=lane; d<DDIM; d+=64){
    float xv = xr[d];
    const float4* g4 = reinterpret_cast<const float4*>(gw + (size_t)d*NEXP);
    float4 a=g4[0], b=g4[1];
    acc[0]=fmaf(xv,a.x,acc[0]); acc[1]=fmaf(xv,a.y,acc[1]);
    acc[2]=fmaf(xv,a.z,acc[2]); acc[3]=fmaf(xv,a.w,acc[3]);
    acc[4]=fmaf(xv,b.x,acc[4]); acc[5]=fmaf(xv,b.y,acc[5]);
    acc[6]=fmaf(xv,b.z,acc[6]); acc[7]=fmaf(xv,b.w,acc[7]);
  }
  #pragma unroll
  for (int s=32;s>0;s>>=1)
    #pragma unroll
    for (int e=0;e<NEXP;e++) acc[e] += __shfl_xor(acc[e], s, 64);
  if (lane==0){
    #pragma unroll
    for (int e=0;e<NEXP;e++) acc[e]+=gb[e];
    int e0=0;
    #pragma unroll
    for (int e=1;e<NEXP;e++) if (acc[e]>acc[e0]) e0=e;   // strict >: ties -> lower idx
    int e1 = (e0==0)?1:0;
    #pragma unroll
    for (int e=0;e<NEXP;e++) if (e!=e0 && acc[e]>acc[e1]) e1=e;
    float p1 = 1.f/(1.f+__expf(acc[e0]-acc[e1]));        // softmax over top2
    float p0 = 1.f-p1;
    tok_e[tok*2]=e0; tok_e[tok*2+1]=e1;
    tok_w[tok*2]=p0; tok_w[tok*2+1]=p1;
  }
}

// ------ rank: deterministic expert-sorted positions via 1-block scan -------
__global__ __launch_bounds__(1024) void rank_kernel(
    const int* __restrict__ tok_e, const float* __restrict__ tok_w,
    int* __restrict__ offsets, int* __restrict__ perm, float* __restrict__ pairw){
  __shared__ u16 hist[NEXP][1024];
  __shared__ int expo[NEXP+1];
  int t = threadIdx.x;
  int c[NEXP];
  #pragma unroll
  for (int e=0;e<NEXP;e++) c[e]=0;
  int base = t*16;
  int le[16];
  #pragma unroll
  for (int i=0;i<16;i++){ le[i]=tok_e[base+i]; c[le[i]]++; }
  #pragma unroll
  for (int e=0;e<NEXP;e++) hist[e][t]=(u16)c[e];
  __syncthreads();
  for (int s=1; s<1024; s<<=1){
    u16 add[NEXP];
    #pragma unroll
    for (int e=0;e<NEXP;e++) add[e] = (t>=s)? hist[e][t-s] : (u16)0;
    __syncthreads();
    #pragma unroll
    for (int e=0;e<NEXP;e++) hist[e][t] += add[e];
    __syncthreads();
  }
  if (t==0){
    int s=0;
    #pragma unroll
    for (int e=0;e<NEXP;e++){ expo[e]=s; s+=hist[e][1023]; }
    expo[NEXP]=s;
    #pragma unroll
    for (int e=0;e<=NEXP;e++) offsets[e]=expo[e];
  }
  __syncthreads();
  int pos[NEXP];
  #pragma unroll
  for (int e=0;e<NEXP;e++) pos[e] = expo[e] + (int)hist[e][t] - c[e];
  #pragma unroll
  for (int i=0;i<16;i++){
    int e=le[i]; int p=pos[e]++;
    perm[p]=(base+i)>>1; pairw[p]=tok_w[base+i];
  }
}

// ------- gather token rows (fp32 -> fp16, expert-sorted, no atomics) -------
__global__ __launch_bounds__(256) void build_gather_kernel(
    const float* __restrict__ x, const int* __restrict__ perm, u16* __restrict__ xg){
  int pos  = (int)((blockIdx.x*256u + threadIdx.x) >> 6);
  int lane = threadIdx.x & 63;
  if (pos >= NPAIR) return;
  int tok = perm[pos];
  const float4* src = reinterpret_cast<const float4*>(x + (size_t)tok*DDIM);
  u16* dst = xg + (size_t)pos*DDIM;
  #pragma unroll
  for (int i=0;i<4;i++){
    float4 v = src[i*64+lane];
    ushort4 o;
    o.x=f2h_bits(v.x); o.y=f2h_bits(v.y); o.z=f2h_bits(v.z); o.w=f2h_bits(v.w);
    *reinterpret_cast<ushort4*>(dst + (size_t)(i*64+lane)*4) = o;
  }
}

// ------- transpose + convert: src fp32 [E][R][C] -> dst fp16 [E][C][R] -----
__global__ __launch_bounds__(256) void transpose_convert_kernel(
    const float* __restrict__ src, u16* __restrict__ dst, int R, int C){
  __shared__ float tile[64][65];
  int e = blockIdx.z;
  const float* s = src + (size_t)e*R*C;
  u16* d = dst + (size_t)e*R*C;
  int c0 = blockIdx.x*64, r0 = blockIdx.y*64;
  int t = threadIdx.x;
  int col4 = (t & 15) * 4, rrow = t >> 4;
  #pragma unroll
  for (int i=0;i<4;i++){
    int row = i*16 + rrow;
    float4 v = *reinterpret_cast<const float4*>(&s[(size_t)(r0+row)*C + c0 + col4]);
    tile[row][col4+0]=v.x; tile[row][col4+1]=v.y;
    tile[row][col4+2]=v.z; tile[row][col4+3]=v.w;
  }
  __syncthreads();
  int cIdx0 = t >> 3, r8 = (t & 7) * 8;
  #pragma unroll
  for (int j=0;j<2;j++){
    int c = j*32 + cIdx0;
    u16x8 o;
    #pragma unroll
    for (int u=0;u<8;u++) o[u] = f2h_bits(tile[r8+u][c]);
    *reinterpret_cast<u16x8*>(&d[(size_t)(c0+c)*R + r0 + r8]) = o;
  }
}

__device__ inline float gelu_tanh(float x){
  float u = 0.7978845608028654f*(x + 0.044715f*x*x*x);
  u = fminf(fmaxf(u,-9.f),9.f);
  float e2 = __expf(2.f*u);
  return 0.5f*x*(1.f + (e2-1.f)/(e2+1.f));
}

// =============== 256x256 8-phase segment GEMM (T2+T3+T4+T5) ================
// C[cnt x Nn] = A[cnt x Kd] * Bt^T, A fp16 rows at Abase[off..],
// Bt fp16 [E][Nn][Kd]. BK=64, 8 waves (2Mx4N), 128KB LDS (2 dbuf x A/B x 2
// halves x 128x64 fp16, st_16x32 swizzle via pre-swizzled global source).
// vmcnt(2) only at phases 4/8: tile T+1 staged ph8',1,2,3; T+2 at ph4..7.
template<int EPI>
__global__ __launch_bounds__(512,2) void moe_gemm8(
    const u16* __restrict__ Abase, const u16* __restrict__ Btbase,
    const float* __restrict__ bias,
    u16* __restrict__ Hout, float* __restrict__ Out,
    const int* __restrict__ offsets, const int* __restrict__ perm,
    const float* __restrict__ pairw){
  constexpr int Kd = (EPI==0)?DDIM:HDIM;
  constexpr int Nn = (EPI==0)?HDIM:DDIM;
  constexpr int NT = Kd/64;          // K-tiles
  constexpr int NIT = NT/2;          // iterations (2 tiles each)
  constexpr int BR = 16, BC = Nn/256, PER_E = BR*BC, G = NEXP*PER_E;
  extern __shared__ __align__(16) char smem[];

  int bid = blockIdx.x;
  int lg = (bid&7)*(G/8) + (bid>>3);          // XCD-bijective (G%8==0)
  int e = lg/PER_E, r = lg%PER_E;
  int bcol = r/BR, brow = r%BR;               // brow inner: B-tile reuse
  int off = offsets[e], cnt = offsets[e+1]-off;
  if (brow*256 >= cnt) return;
  int lane = threadIdx.x&63, wid = (int)threadIdx.x>>6;
  int wr = wid>>2, wc = wid&3;                // 2x4 wave grid

  // ---- staging setup: linear LDS dest, inverse-swizzled global source ----
  int l8 = lane>>3;
  int kof = ((lane&7)*8) ^ ((lane>=32)?16:0);   // pre-swizzled k-offset
  const u16* aS[2][2]; const u16* bS[2][2];
  #pragma unroll
  for (int h=0;h<2;h++)
    #pragma unroll
    for (int j=0;j<2;j++){
      int row = h*128 + wid*8 + j*64 + l8;      // chunk c=wid+j*8, row=c*8+l8
      aS[h][j] = Abase + (size_t)(off + min(brow*256+row, cnt-1))*Kd + kof;
      bS[h][j] = Btbase + (size_t)e*Nn*Kd + (size_t)(bcol*256+row)*Kd + kof;
    }
  char* ldsA = smem; char* ldsB = smem + 65536;
  int dst0 = wid*1024 + lane*16, dst1 = 8192 + wid*1024 + lane*16;

#define STG_A(h, tile, buf) { \
    gload_lds16(aS[h][0]+(size_t)(tile)*64, ldsA+(buf)*32768+(h)*16384+dst0); \
    gload_lds16(aS[h][1]+(size_t)(tile)*64, ldsA+(buf)*32768+(h)*16384+dst1); }
#define STG_B(h, tile, buf) { \
    gload_lds16(bS[h][0]+(size_t)(tile)*64, ldsB+(buf)*32768+(h)*16384+dst0); \
    gload_lds16(bS[h][1]+(size_t)(tile)*64, ldsB+(buf)*32768+(h)*16384+dst1); }

  // ---- fragment read setup (swizzled ds_read_b128) ----
  int lr = lane&15, hi16 = (lane>>4)*16, sx = ((lane>>2)&1)<<5;
  const char* aRd = ldsA + wr*16384;           // wave's A half
  const char* bRd = ldsB + (wc>>1)*16384;      // wave's B half
  f16x8 a[4][2], b[2][2][2];
  f32x4 acc[8][4] = {};

#define RD_A(mh, buf) { _Pragma("unroll") for (int mf=0;mf<4;mf++) \
    _Pragma("unroll") for (int ks=0;ks<2;ks++) \
      a[mf][ks] = *(const f16x8*)(aRd + (buf)*32768 + \
        ((mh)*64+mf*16+lr)*128 + ((ks*64+hi16)^sx)); }
#define RD_B(np, buf) { _Pragma("unroll") for (int nf=0;nf<2;nf++) \
    _Pragma("unroll") for (int ks=0;ks<2;ks++) \
      b[np][nf][ks] = *(const f16x8*)(bRd + (buf)*32768 + \
        (((wc&1)*64+((np)*2+nf)*16+lr)*128) + ((ks*64+hi16)^sx)); }
#define MM(mh, np) { _Pragma("unroll") for (int mf=0;mf<4;mf++) \
    _Pragma("unroll") for (int nf=0;nf<2;nf++) \
    _Pragma("unroll") for (int ks=0;ks<2;ks++) \
      acc[(mh)*4+mf][(np)*2+nf] = __builtin_amdgcn_mfma_f32_16x16x32_f16( \
        a[mf][ks], b[np][nf][ks], acc[(mh)*4+mf][(np)*2+nf], 0,0,0); }

#define BAR   __builtin_amdgcn_s_barrier()
#define LGKM0 { asm volatile("s_waitcnt lgkmcnt(0)" ::: "memory"); \
                __builtin_amdgcn_sched_barrier(0); }
#define VM2   { asm volatile("s_waitcnt vmcnt(2)" ::: "memory"); \
                __builtin_amdgcn_sched_barrier(0); }
#define PRIO1 __builtin_amdgcn_s_setprio(1)
#define PRIO0 __builtin_amdgcn_s_setprio(0)

  // prologue: tile0 full -> buf0, tile1 A-half0 -> buf1; wait tile0 (vmcnt(2))
  STG_A(0,0,0); STG_A(1,0,0); STG_B(0,0,0); STG_B(1,0,0);
  STG_A(0,1,1);
  VM2; BAR;

  for (int it=0; it<NIT; ++it){
    int t1 = 2*it+1, t2 = (2*it+2)&(NT-1), t3 = (2*it+3)&(NT-1); // wrap tail
    // P1..P4: compute tile 2it (buf0); stage t1 -> buf1, then t2 -> buf0
    RD_A(0,0); RD_B(0,0); STG_A(1,t1,1); BAR; LGKM0; PRIO1; MM(0,0); PRIO0; BAR;
    RD_B(1,0);            STG_B(0,t1,1); BAR; LGKM0; PRIO1; MM(0,1); PRIO0; BAR;
    RD_A(1,0);            STG_B(1,t1,1); BAR; LGKM0; PRIO1; MM(1,1); PRIO0; BAR;
                          STG_A(0,t2,0); BAR;        PRIO1; MM(1,0); PRIO0; VM2; BAR;
    // P5..P8: compute tile 2it+1 (buf1); stage t2 -> buf0, t3 A0 -> buf1
    RD_A(0,1); RD_B(0,1); STG_A(1,t2,0); BAR; LGKM0; PRIO1; MM(0,0); PRIO0; BAR;
    RD_B(1,1);            STG_B(0,t2,0); BAR; LGKM0; PRIO1; MM(0,1); PRIO0; BAR;
    RD_A(1,1);            STG_B(1,t2,0); BAR; LGKM0; PRIO1; MM(1,1); PRIO0; BAR;
                          STG_A(0,t3,1); BAR;        PRIO1; MM(1,0); PRIO0; VM2; BAR;
  }

  // epilogue: C row = brow*256 + wr*128 + am*16 + (lane>>4)*4 + j
  //           C col = bcol*256 + wc*64 + an*16 + (lane&15)
  int lr4 = (lane>>4)*4, lc = lane&15;
  #pragma unroll
  for (int am=0;am<8;am++){
    #pragma unroll
    for (int j=0;j<4;j++){
      int grow = brow*256 + wr*128 + am*16 + lr4 + j;
      if (grow < cnt){
        int p = off + grow;
        if (EPI==0){
          size_t rbase = (size_t)p*Nn;
          #pragma unroll
          for (int an=0;an<4;an++){
            int colg = bcol*256 + wc*64 + an*16 + lc;
            float v = acc[am][an][j] + bias[e*Nn + colg];
            Hout[rbase + colg] = f2h_bits(gelu_tanh(v));
          }
        } else {
          int tok = perm[p]; float wv = pairw[p];
          size_t obase = (size_t)tok*Nn;
          #pragma unroll
          for (int an=0;an<4;an++){
            int colg = bcol*256 + wc*64 + an*16 + lc;
            atomicAdd(&Out[obase + colg], wv*(acc[am][an][j] + bias[e*Nn + colg]));
          }
        }
      }
    }
  }
#undef STG_A
#undef STG_B
#undef RD_A
#undef RD_B
#undef MM
#undef BAR
#undef LGKM0
#undef VM2
#undef PRIO1
#undef PRIO0
}

extern "C" void kernel_launch(void* const* d_in, const int* in_sizes, int n_in,
                              void* d_out, int out_size, void* d_ws, size_t ws_size,
                              hipStream_t stream){
  const float* x  = (const float*)d_in[0];
  const float* gw = (const float*)d_in[1];
  const float* gb = (const float*)d_in[2];
  const float* w1 = (const float*)d_in[3];
  const float* b1 = (const float*)d_in[4];
  const float* w2 = (const float*)d_in[5];
  const float* b2 = (const float*)d_in[6];
  float* out = (float*)d_out;
  char* ws = (char*)d_ws;

  // workspace layout
  int*   offsets = (int*)(ws + 64);
  int*   tok_e   = (int*)(ws + 256);
  float* tok_w   = (float*)(ws + 256 + 1*65536);
  int*   perm    = (int*)(ws + 256 + 2*65536);
  float* pairw   = (float*)(ws + 256 + 3*65536);
  size_t base = 256 + 4*65536;
  u16* xg   = (u16*)(ws + base);                                     // 32 MiB
  u16* w1t  = (u16*)(ws + base + 33554432ull);                       // 64 MiB
  u16* w2t  = (u16*)(ws + base + 33554432ull + 67108864ull);         // 64 MiB
  u16* hbuf = (u16*)(ws + base + 33554432ull + 2*67108864ull);       // 128 MiB
  size_t need = base + 33554432ull + 2*67108864ull + 134217728ull;

  hipMemsetAsync(d_out, 0, (size_t)out_size*sizeof(float), stream);
  if (ws_size < need) return;   // graceful fail: zeros out

  hipFuncSetAttribute(reinterpret_cast<const void*>(moe_gemm8<0>),
                      hipFuncAttributeMaxDynamicSharedMemorySize, 131072);
  hipFuncSetAttribute(reinterpret_cast<const void*>(moe_gemm8<1>),
                      hipFuncAttributeMaxDynamicSharedMemorySize, 131072);

  gate_kernel<<<N_TOK/4, 256, 0, stream>>>(x, gw, gb, tok_e, tok_w);
  rank_kernel<<<1, 1024, 0, stream>>>(tok_e, tok_w, offsets, perm, pairw);
  build_gather_kernel<<<NPAIR/4, 256, 0, stream>>>(x, perm, xg);
  transpose_convert_kernel<<<dim3(HDIM/64, DDIM/64, NEXP), 256, 0, stream>>>(w1, w1t, DDIM, HDIM);
  transpose_convert_kernel<<<dim3(DDIM/64, HDIM/64, NEXP), 256, 0, stream>>>(w2, w2t, HDIM, DDIM);
  moe_gemm8<0><<<NEXP*16*(HDIM/256), 512, 131072, stream>>>(
      xg, w1t, b1, hbuf, nullptr, offsets, perm, pairw);
  moe_gemm8<1><<<NEXP*16*(DDIM/256), 512, 131072, stream>>>(
      hbuf, w2t, b2, nullptr, out, offsets, perm, pairw);
}

// Round 4
// 710.621 us; speedup vs baseline: 1.4115x; 1.0609x over previous
//
#include <hip/hip_runtime.h>
#include <hip/hip_fp16.h>

#define N_TOK 8192
#define DDIM  1024
#define HDIM  4096
#define NEXP  8
#define NPAIR (N_TOK*2)

typedef unsigned short u16;
typedef _Float16 f16x8 __attribute__((ext_vector_type(8)));
typedef float    f32x4 __attribute__((ext_vector_type(4)));
typedef unsigned short u16x8 __attribute__((ext_vector_type(8)));

__device__ inline u16 f2h_bits(float f){
  _Float16 h = (_Float16)f;
  return __builtin_bit_cast(unsigned short, h);
}

typedef const __attribute__((address_space(1))) void* gas1_cvp;
typedef       __attribute__((address_space(3))) void* gas3_vp;
__device__ inline void gload_lds16(const void* g, void* l){
  __builtin_amdgcn_global_load_lds((gas1_cvp)g, (gas3_vp)l, 16, 0, 0);
}

// ---------------- gating: logits -> top2 + softmax (no atomics) ------------
__global__ __launch_bounds__(256) void gate_kernel(
    const float* __restrict__ x, const float* __restrict__ gw, const float* __restrict__ gb,
    int* __restrict__ tok_e, float* __restrict__ tok_w){
  int tok  = (int)((blockIdx.x*256u + threadIdx.x) >> 6);
  int lane = threadIdx.x & 63;
  if (tok >= N_TOK) return;
  const float* xr = x + (size_t)tok*DDIM;
  float acc[NEXP];
  #pragma unroll
  for (int e=0;e<NEXP;e++) acc[e]=0.f;
  for (int d=lane; d<DDIM; d+=64){
    float xv = xr[d];
    const float4* g4 = reinterpret_cast<const float4*>(gw + (size_t)d*NEXP);
    float4 a=g4[0], b=g4[1];
    acc[0]=fmaf(xv,a.x,acc[0]); acc[1]=fmaf(xv,a.y,acc[1]);
    acc[2]=fmaf(xv,a.z,acc[2]); acc[3]=fmaf(xv,a.w,acc[3]);
    acc[4]=fmaf(xv,b.x,acc[4]); acc[5]=fmaf(xv,b.y,acc[5]);
    acc[6]=fmaf(xv,b.z,acc[6]); acc[7]=fmaf(xv,b.w,acc[7]);
  }
  #pragma unroll
  for (int s=32;s>0;s>>=1)
    #pragma unroll
    for (int e=0;e<NEXP;e++) acc[e] += __shfl_xor(acc[e], s, 64);
  if (lane==0){
    #pragma unroll
    for (int e=0;e<NEXP;e++) acc[e]+=gb[e];
    int e0=0;
    #pragma unroll
    for (int e=1;e<NEXP;e++) if (acc[e]>acc[e0]) e0=e;   // strict >: ties -> lower idx
    int e1 = (e0==0)?1:0;
    #pragma unroll
    for (int e=0;e<NEXP;e++) if (e!=e0 && acc[e]>acc[e1]) e1=e;
    float p1 = 1.f/(1.f+__expf(acc[e0]-acc[e1]));        // softmax over top2
    float p0 = 1.f-p1;
    tok_e[tok*2]=e0; tok_e[tok*2+1]=e1;
    tok_w[tok*2]=p0; tok_w[tok*2+1]=p1;
  }
}

// ------ rank: deterministic expert-sorted positions via 1-block scan -------
__global__ __launch_bounds__(1024) void rank_kernel(
    const int* __restrict__ tok_e, const float* __restrict__ tok_w,
    int* __restrict__ offsets, int* __restrict__ perm, float* __restrict__ pairw){
  __shared__ u16 hist[NEXP][1024];
  __shared__ int expo[NEXP+1];
  int t = threadIdx.x;
  int c[NEXP];
  #pragma unroll
  for (int e=0;e<NEXP;e++) c[e]=0;
  int base = t*16;
  int le[16];
  #pragma unroll
  for (int i=0;i<16;i++){ le[i]=tok_e[base+i]; c[le[i]]++; }
  #pragma unroll
  for (int e=0;e<NEXP;e++) hist[e][t]=(u16)c[e];
  __syncthreads();
  for (int s=1; s<1024; s<<=1){
    u16 add[NEXP];
    #pragma unroll
    for (int e=0;e<NEXP;e++) add[e] = (t>=s)? hist[e][t-s] : (u16)0;
    __syncthreads();
    #pragma unroll
    for (int e=0;e<NEXP;e++) hist[e][t] += add[e];
    __syncthreads();
  }
  if (t==0){
    int s=0;
    #pragma unroll
    for (int e=0;e<NEXP;e++){ expo[e]=s; s+=hist[e][1023]; }
    expo[NEXP]=s;
    #pragma unroll
    for (int e=0;e<=NEXP;e++) offsets[e]=expo[e];
  }
  __syncthreads();
  int pos[NEXP];
  #pragma unroll
  for (int e=0;e<NEXP;e++) pos[e] = expo[e] + (int)hist[e][t] - c[e];
  #pragma unroll
  for (int i=0;i<16;i++){
    int e=le[i]; int p=pos[e]++;
    perm[p]=(base+i)>>1; pairw[p]=tok_w[base+i];
  }
}

// ------- gather token rows (fp32 -> fp16, expert-sorted, no atomics) -------
__global__ __launch_bounds__(256) void build_gather_kernel(
    const float* __restrict__ x, const int* __restrict__ perm, u16* __restrict__ xg){
  int pos  = (int)((blockIdx.x*256u + threadIdx.x) >> 6);
  int lane = threadIdx.x & 63;
  if (pos >= NPAIR) return;
  int tok = perm[pos];
  const float4* src = reinterpret_cast<const float4*>(x + (size_t)tok*DDIM);
  u16* dst = xg + (size_t)pos*DDIM;
  #pragma unroll
  for (int i=0;i<4;i++){
    float4 v = src[i*64+lane];
    ushort4 o;
    o.x=f2h_bits(v.x); o.y=f2h_bits(v.y); o.z=f2h_bits(v.z); o.w=f2h_bits(v.w);
    *reinterpret_cast<ushort4*>(dst + (size_t)(i*64+lane)*4) = o;
  }
}

// ------- transpose + convert: src fp32 [E][R][C] -> dst fp16 [E][C][R] -----
__global__ __launch_bounds__(256) void transpose_convert_kernel(
    const float* __restrict__ src, u16* __restrict__ dst, int R, int C){
  __shared__ float tile[64][65];
  int e = blockIdx.z;
  const float* s = src + (size_t)e*R*C;
  u16* d = dst + (size_t)e*R*C;
  int c0 = blockIdx.x*64, r0 = blockIdx.y*64;
  int t = threadIdx.x;
  int col4 = (t & 15) * 4, rrow = t >> 4;
  #pragma unroll
  for (int i=0;i<4;i++){
    int row = i*16 + rrow;
    float4 v = *reinterpret_cast<const float4*>(&s[(size_t)(r0+row)*C + c0 + col4]);
    tile[row][col4+0]=v.x; tile[row][col4+1]=v.y;
    tile[row][col4+2]=v.z; tile[row][col4+3]=v.w;
  }
  __syncthreads();
  int cIdx0 = t >> 3, r8 = (t & 7) * 8;
  #pragma unroll
  for (int j=0;j<2;j++){
    int c = j*32 + cIdx0;
    u16x8 o;
    #pragma unroll
    for (int u=0;u<8;u++) o[u] = f2h_bits(tile[r8+u][c]);
    *reinterpret_cast<u16x8*>(&d[(size_t)(c0+c)*R + r0 + r8]) = o;
  }
}

__device__ inline float gelu_tanh(float x){
  float u = 0.7978845608028654f*(x + 0.044715f*x*x*x);
  u = fminf(fmaxf(u,-9.f),9.f);
  float e2 = __expf(2.f*u);
  return 0.5f*x*(1.f + (e2-1.f)/(e2+1.f));
}

// =============== 256x256 8-phase segment GEMM (T2+T3+T4+T5) ================
// LDS: per 16KB half-tile (128 rows x 64 fp16), TRUE st_16x32 subtiled layout:
//   addr(r,c) = ((r>>4)*2+(c>>5))*1024 + (r&15)*64 + (((c&31)*2)^((r>>3&1)<<5))
// Staged via linear global_load_lds dest (chunk c == subtile c) with the
// inverse permutation applied to the GLOBAL source address (rule 21).
// Read & write both land 8 accesses/bank (conflict-free minimum).
template<int EPI>
__global__ __launch_bounds__(512,2) void moe_gemm8(
    const u16* __restrict__ Abase, const u16* __restrict__ Btbase,
    const float* __restrict__ bias,
    u16* __restrict__ Hout, float* __restrict__ Out,
    const int* __restrict__ offsets, const int* __restrict__ perm,
    const float* __restrict__ pairw){
  constexpr int Kd = (EPI==0)?DDIM:HDIM;
  constexpr int Nn = (EPI==0)?HDIM:DDIM;
  constexpr int NT = Kd/64;          // K-tiles
  constexpr int NIT = NT/2;          // iterations (2 tiles each)
  constexpr int BR = 16, BC = Nn/256, PER_E = BR*BC, G = NEXP*PER_E;
  extern __shared__ __align__(16) char smem[];

  int bid = blockIdx.x;
  int lg = (bid&7)*(G/8) + (bid>>3);          // XCD-bijective (G%8==0)
  int e = lg/PER_E, r = lg%PER_E;
  int bcol = r/BR, brow = r%BR;               // brow inner: B-tile reuse
  int off = offsets[e], cnt = offsets[e+1]-off;
  if (brow*256 >= cnt) return;
  int lane = threadIdx.x&63, wid = (int)threadIdx.x>>6;
  int wr = wid>>2, wc = wid&3;                // 2x4 wave grid

  // ---- staging: linear LDS dest (chunk c = subtile c), pre-swizzled source --
  // chunk c (j=0: c=wid, j=1: c=wid+8): row = (c>>1)*16 + (lane>>2),
  // kelem = (c&1)*32 + ((lane&3)*8 ^ ((lane>>5)&1)*16)
  int l4 = lane>>2;
  int kof = (wid&1)*32 + (((lane&3)*8) ^ (((lane>>5)&1)*16));
  const u16* aS[2][2]; const u16* bS[2][2];
  #pragma unroll
  for (int h=0;h<2;h++)
    #pragma unroll
    for (int j=0;j<2;j++){
      int row = h*128 + ((wid>>1) + j*4)*16 + l4;
      aS[h][j] = Abase + (size_t)(off + min(brow*256+row, cnt-1))*Kd + kof;
      bS[h][j] = Btbase + (size_t)e*Nn*Kd + (size_t)(bcol*256+row)*Kd + kof;
    }
  char* ldsA = smem; char* ldsB = smem + 65536;
  int dst0 = wid*1024 + lane*16, dst1 = 8192 + wid*1024 + lane*16;

#define STG_A(h, tile, buf) { \
    gload_lds16(aS[h][0]+(size_t)(tile)*64, ldsA+(buf)*32768+(h)*16384+dst0); \
    gload_lds16(aS[h][1]+(size_t)(tile)*64, ldsA+(buf)*32768+(h)*16384+dst1); }
#define STG_B(h, tile, buf) { \
    gload_lds16(bS[h][0]+(size_t)(tile)*64, ldsB+(buf)*32768+(h)*16384+dst0); \
    gload_lds16(bS[h][1]+(size_t)(tile)*64, ldsB+(buf)*32768+(h)*16384+dst1); }

  // ---- fragment reads (subtiled+swizzled ds_read_b128) ----
  int lr = lane&15;
  int rdq = lr*64 + (((lane>>4)*16) ^ (((lane>>3)&1)<<5));
  const char* aRd = ldsA + wr*16384;           // wave's A half
  const char* bRd = ldsB + (wc>>1)*16384;      // wave's B half
  f16x8 a[4][2], b[2][2][2];
  f32x4 acc[8][4] = {};

#define RD_A(mh, buf) { _Pragma("unroll") for (int mf=0;mf<4;mf++) \
    _Pragma("unroll") for (int ks=0;ks<2;ks++) \
      a[mf][ks] = *(const f16x8*)(aRd + (buf)*32768 + \
        (mh)*8192 + mf*2048 + ks*1024 + rdq); }
#define RD_B(np, buf) { _Pragma("unroll") for (int nf=0;nf<2;nf++) \
    _Pragma("unroll") for (int ks=0;ks<2;ks++) \
      b[np][nf][ks] = *(const f16x8*)(bRd + (buf)*32768 + \
        (wc&1)*8192 + ((np)*2+nf)*2048 + ks*1024 + rdq); }
#define MM(mh, np) { _Pragma("unroll") for (int mf=0;mf<4;mf++) \
    _Pragma("unroll") for (int nf=0;nf<2;nf++) \
    _Pragma("unroll") for (int ks=0;ks<2;ks++) \
      acc[(mh)*4+mf][(np)*2+nf] = __builtin_amdgcn_mfma_f32_16x16x32_f16( \
        a[mf][ks], b[np][nf][ks], acc[(mh)*4+mf][(np)*2+nf], 0,0,0); }

#define BAR   __builtin_amdgcn_s_barrier()
#define LGKM0 { asm volatile("s_waitcnt lgkmcnt(0)" ::: "memory"); \
                __builtin_amdgcn_sched_barrier(0); }
#define VM2   { asm volatile("s_waitcnt vmcnt(2)" ::: "memory"); \
                __builtin_amdgcn_sched_barrier(0); }
#define PRIO1 __builtin_amdgcn_s_setprio(1)
#define PRIO0 __builtin_amdgcn_s_setprio(0)

  // prologue: tile0 full -> buf0, tile1 A-half0 -> buf1; wait tile0 (vmcnt(2))
  STG_A(0,0,0); STG_A(1,0,0); STG_B(0,0,0); STG_B(1,0,0);
  STG_A(0,1,1);
  VM2; BAR;

  for (int it=0; it<NIT; ++it){
    int t1 = 2*it+1, t2 = (2*it+2)&(NT-1), t3 = (2*it+3)&(NT-1); // wrap tail
    // P1..P4: compute tile 2it (buf0); stage t1 -> buf1, then t2 -> buf0
    RD_A(0,0); RD_B(0,0); STG_A(1,t1,1); BAR; LGKM0; PRIO1; MM(0,0); PRIO0; BAR;
    RD_B(1,0);            STG_B(0,t1,1); BAR; LGKM0; PRIO1; MM(0,1); PRIO0; BAR;
    RD_A(1,0);            STG_B(1,t1,1); BAR; LGKM0; PRIO1; MM(1,1); PRIO0; BAR;
                          STG_A(0,t2,0); BAR;        PRIO1; MM(1,0); PRIO0; VM2; BAR;
    // P5..P8: compute tile 2it+1 (buf1); stage t2 -> buf0, t3 A0 -> buf1
    RD_A(0,1); RD_B(0,1); STG_A(1,t2,0); BAR; LGKM0; PRIO1; MM(0,0); PRIO0; BAR;
    RD_B(1,1);            STG_B(0,t2,0); BAR; LGKM0; PRIO1; MM(0,1); PRIO0; BAR;
    RD_A(1,1);            STG_B(1,t2,0); BAR; LGKM0; PRIO1; MM(1,1); PRIO0; BAR;
                          STG_A(0,t3,1); BAR;        PRIO1; MM(1,0); PRIO0; VM2; BAR;
  }

  // epilogue: C row = brow*256 + wr*128 + am*16 + (lane>>4)*4 + j
  //           C col = bcol*256 + wc*64 + an*16 + (lane&15)
  int lr4 = (lane>>4)*4, lc = lane&15;
  #pragma unroll
  for (int am=0;am<8;am++){
    #pragma unroll
    for (int j=0;j<4;j++){
      int grow = brow*256 + wr*128 + am*16 + lr4 + j;
      if (grow < cnt){
        int p = off + grow;
        if (EPI==0){
          size_t rbase = (size_t)p*Nn;
          #pragma unroll
          for (int an=0;an<4;an++){
            int colg = bcol*256 + wc*64 + an*16 + lc;
            float v = acc[am][an][j] + bias[e*Nn + colg];
            Hout[rbase + colg] = f2h_bits(gelu_tanh(v));
          }
        } else {
          int tok = perm[p]; float wv = pairw[p];
          size_t obase = (size_t)tok*Nn;
          #pragma unroll
          for (int an=0;an<4;an++){
            int colg = bcol*256 + wc*64 + an*16 + lc;
            atomicAdd(&Out[obase + colg], wv*(acc[am][an][j] + bias[e*Nn + colg]));
          }
        }
      }
    }
  }
#undef STG_A
#undef STG_B
#undef RD_A
#undef RD_B
#undef MM
#undef BAR
#undef LGKM0
#undef VM2
#undef PRIO1
#undef PRIO0
}

extern "C" void kernel_launch(void* const* d_in, const int* in_sizes, int n_in,
                              void* d_out, int out_size, void* d_ws, size_t ws_size,
                              hipStream_t stream){
  const float* x  = (const float*)d_in[0];
  const float* gw = (const float*)d_in[1];
  const float* gb = (const float*)d_in[2];
  const float* w1 = (const float*)d_in[3];
  const float* b1 = (const float*)d_in[4];
  const float* w2 = (const float*)d_in[5];
  const float* b2 = (const float*)d_in[6];
  float* out = (float*)d_out;
  char* ws = (char*)d_ws;

  // workspace layout
  int*   offsets = (int*)(ws + 64);
  int*   tok_e   = (int*)(ws + 256);
  float* tok_w   = (float*)(ws + 256 + 1*65536);
  int*   perm    = (int*)(ws + 256 + 2*65536);
  float* pairw   = (float*)(ws + 256 + 3*65536);
  size_t base = 256 + 4*65536;
  u16* xg   = (u16*)(ws + base);                                     // 32 MiB
  u16* w1t  = (u16*)(ws + base + 33554432ull);                       // 64 MiB
  u16* w2t  = (u16*)(ws + base + 33554432ull + 67108864ull);         // 64 MiB
  u16* hbuf = (u16*)(ws + base + 33554432ull + 2*67108864ull);       // 128 MiB
  size_t need = base + 33554432ull + 2*67108864ull + 134217728ull;

  hipMemsetAsync(d_out, 0, (size_t)out_size*sizeof(float), stream);
  if (ws_size < need) return;   // graceful fail: zeros out

  hipFuncSetAttribute(reinterpret_cast<const void*>(moe_gemm8<0>),
                      hipFuncAttributeMaxDynamicSharedMemorySize, 131072);
  hipFuncSetAttribute(reinterpret_cast<const void*>(moe_gemm8<1>),
                      hipFuncAttributeMaxDynamicSharedMemorySize, 131072);

  gate_kernel<<<N_TOK/4, 256, 0, stream>>>(x, gw, gb, tok_e, tok_w);
  rank_kernel<<<1, 1024, 0, stream>>>(tok_e, tok_w, offsets, perm, pairw);
  build_gather_kernel<<<NPAIR/4, 256, 0, stream>>>(x, perm, xg);
  transpose_convert_kernel<<<dim3(HDIM/64, DDIM/64, NEXP), 256, 0, stream>>>(w1, w1t, DDIM, HDIM);
  transpose_convert_kernel<<<dim3(DDIM/64, HDIM/64, NEXP), 256, 0, stream>>>(w2, w2t, HDIM, DDIM);
  moe_gemm8<0><<<NEXP*16*(HDIM/256), 512, 131072, stream>>>(
      xg, w1t, b1, hbuf, nullptr, offsets, perm, pairw);
  moe_gemm8<1><<<NEXP*16*(DDIM/256), 512, 131072, stream>>>(
      hbuf, w2t, b2, nullptr, out, offsets, perm, pairw);
}

// Round 6
// 696.753 us; speedup vs baseline: 1.4396x; 1.0199x over previous
//
#include <hip/hip_runtime.h>
#include <hip/hip_fp16.h>

#define N_TOK 8192
#define DDIM  1024
#define HDIM  4096
#define NEXP  8
#define NPAIR (N_TOK*2)

typedef unsigned short u16;
typedef _Float16 f16x8 __attribute__((ext_vector_type(8)));
typedef float    f32x4 __attribute__((ext_vector_type(4)));
typedef unsigned short u16x8 __attribute__((ext_vector_type(8)));

__device__ inline u16 f2h_bits(float f){
  _Float16 h = (_Float16)f;
  return __builtin_bit_cast(unsigned short, h);
}

typedef const __attribute__((address_space(1))) void* gas1_cvp;
typedef       __attribute__((address_space(3))) void* gas3_vp;
__device__ inline void gload_lds16(const void* g, void* l){
  __builtin_amdgcn_global_load_lds((gas1_cvp)g, (gas3_vp)l, 16, 0, 0);
}

// ---------------- gating: logits -> top2 + softmax (no atomics) ------------
__global__ __launch_bounds__(256) void gate_kernel(
    const float* __restrict__ x, const float* __restrict__ gw, const float* __restrict__ gb,
    int* __restrict__ tok_e, float* __restrict__ tok_w){
  int tok  = (int)((blockIdx.x*256u + threadIdx.x) >> 6);
  int lane = threadIdx.x & 63;
  if (tok >= N_TOK) return;
  const float* xr = x + (size_t)tok*DDIM;
  float acc[NEXP];
  #pragma unroll
  for (int e=0;e<NEXP;e++) acc[e]=0.f;
  for (int d=lane; d<DDIM; d+=64){
    float xv = xr[d];
    const float4* g4 = reinterpret_cast<const float4*>(gw + (size_t)d*NEXP);
    float4 a=g4[0], b=g4[1];
    acc[0]=fmaf(xv,a.x,acc[0]); acc[1]=fmaf(xv,a.y,acc[1]);
    acc[2]=fmaf(xv,a.z,acc[2]); acc[3]=fmaf(xv,a.w,acc[3]);
    acc[4]=fmaf(xv,b.x,acc[4]); acc[5]=fmaf(xv,b.y,acc[5]);
    acc[6]=fmaf(xv,b.z,acc[6]); acc[7]=fmaf(xv,b.w,acc[7]);
  }
  #pragma unroll
  for (int s=32;s>0;s>>=1)
    #pragma unroll
    for (int e=0;e<NEXP;e++) acc[e] += __shfl_xor(acc[e], s, 64);
  if (lane==0){
    #pragma unroll
    for (int e=0;e<NEXP;e++) acc[e]+=gb[e];
    int e0=0;
    #pragma unroll
    for (int e=1;e<NEXP;e++) if (acc[e]>acc[e0]) e0=e;   // strict >: ties -> lower idx
    int e1 = (e0==0)?1:0;
    #pragma unroll
    for (int e=0;e<NEXP;e++) if (e!=e0 && acc[e]>acc[e1]) e1=e;
    float p1 = 1.f/(1.f+__expf(acc[e0]-acc[e1]));        // softmax over top2
    float p0 = 1.f-p1;
    tok_e[tok*2]=e0; tok_e[tok*2+1]=e1;
    tok_w[tok*2]=p0; tok_w[tok*2+1]=p1;
  }
}

// ------ rank: deterministic expert-sorted positions via 1-block scan -------
__global__ __launch_bounds__(1024) void rank_kernel(
    const int* __restrict__ tok_e, const float* __restrict__ tok_w,
    int* __restrict__ offsets, int* __restrict__ perm, float* __restrict__ pairw){
  __shared__ u16 hist[NEXP][1024];
  __shared__ int expo[NEXP+1];
  int t = threadIdx.x;
  int c[NEXP];
  #pragma unroll
  for (int e=0;e<NEXP;e++) c[e]=0;
  int base = t*16;
  int le[16];
  #pragma unroll
  for (int i=0;i<16;i++){ le[i]=tok_e[base+i]; c[le[i]]++; }
  #pragma unroll
  for (int e=0;e<NEXP;e++) hist[e][t]=(u16)c[e];
  __syncthreads();
  for (int s=1; s<1024; s<<=1){
    u16 add[NEXP];
    #pragma unroll
    for (int e=0;e<NEXP;e++) add[e] = (t>=s)? hist[e][t-s] : (u16)0;
    __syncthreads();
    #pragma unroll
    for (int e=0;e<NEXP;e++) hist[e][t] += add[e];
    __syncthreads();
  }
  if (t==0){
    int s=0;
    #pragma unroll
    for (int e=0;e<NEXP;e++){ expo[e]=s; s+=hist[e][1023]; }
    expo[NEXP]=s;
    #pragma unroll
    for (int e=0;e<=NEXP;e++) offsets[e]=expo[e];
  }
  __syncthreads();
  int pos[NEXP];
  #pragma unroll
  for (int e=0;e<NEXP;e++) pos[e] = expo[e] + (int)hist[e][t] - c[e];
  #pragma unroll
  for (int i=0;i<16;i++){
    int e=le[i]; int p=pos[e]++;
    perm[p]=(base+i)>>1; pairw[p]=tok_w[base+i];
  }
}

// ------- gather token rows (fp32 -> fp16, expert-sorted, no atomics) -------
__global__ __launch_bounds__(256) void build_gather_kernel(
    const float* __restrict__ x, const int* __restrict__ perm, u16* __restrict__ xg){
  int pos  = (int)((blockIdx.x*256u + threadIdx.x) >> 6);
  int lane = threadIdx.x & 63;
  if (pos >= NPAIR) return;
  int tok = perm[pos];
  const float4* src = reinterpret_cast<const float4*>(x + (size_t)tok*DDIM);
  u16* dst = xg + (size_t)pos*DDIM;
  #pragma unroll
  for (int i=0;i<4;i++){
    float4 v = src[i*64+lane];
    ushort4 o;
    o.x=f2h_bits(v.x); o.y=f2h_bits(v.y); o.z=f2h_bits(v.z); o.w=f2h_bits(v.w);
    *reinterpret_cast<ushort4*>(dst + (size_t)(i*64+lane)*4) = o;
  }
}

// ------- transpose + convert: src fp32 [E][R][C] -> dst fp16 [E][C][R] -----
__global__ __launch_bounds__(256) void transpose_convert_kernel(
    const float* __restrict__ src, u16* __restrict__ dst, int R, int C){
  __shared__ float tile[64][65];
  int e = blockIdx.z;
  const float* s = src + (size_t)e*R*C;
  u16* d = dst + (size_t)e*R*C;
  int c0 = blockIdx.x*64, r0 = blockIdx.y*64;
  int t = threadIdx.x;
  int col4 = (t & 15) * 4, rrow = t >> 4;
  #pragma unroll
  for (int i=0;i<4;i++){
    int row = i*16 + rrow;
    float4 v = *reinterpret_cast<const float4*>(&s[(size_t)(r0+row)*C + c0 + col4]);
    tile[row][col4+0]=v.x; tile[row][col4+1]=v.y;
    tile[row][col4+2]=v.z; tile[row][col4+3]=v.w;
  }
  __syncthreads();
  int cIdx0 = t >> 3, r8 = (t & 7) * 8;
  #pragma unroll
  for (int j=0;j<2;j++){
    int c = j*32 + cIdx0;
    u16x8 o;
    #pragma unroll
    for (int u=0;u<8;u++) o[u] = f2h_bits(tile[r8+u][c]);
    *reinterpret_cast<u16x8*>(&d[(size_t)(c0+c)*R + r0 + r8]) = o;
  }
}

__device__ inline float gelu_tanh(float x){
  float u = 0.7978845608028654f*(x + 0.044715f*x*x*x);
  u = fminf(fmaxf(u,-9.f),9.f);
  float e2 = __expf(2.f*u);
  return 0.5f*x*(1.f + (e2-1.f)/(e2+1.f));
}

// =============== 256x256 segment GEMM, m201 cadence (race-free) ============
// 4 phases/K-tile, 2 loads staged per phase, vmcnt(6) once per K-tile.
// dst0 = subtiles 0-7 = half-rows 0-63 (read at P1); dst1 = subtiles 8-15 =
// half-rows 64-127 (read at P3). Phase staging map (group computing tile T):
//   P1: A-dst1(T+1)->other   (other buf fully read last group)
//   P2: A-dst0(T+2)->cur     (cur A rows 0-63 freed by P1 reads)
//   P3: B-half0(T+2)->cur    (all B reads done by end of P2)
//   P4: B-half1(T+2)->cur ; vmcnt(6) retires exactly tile T+1 (3-phase slack)
// Every phase's LDS writes are disjoint from that phase's LDS reads.
template<int EPI>
__global__ __launch_bounds__(512,2) void moe_gemm8(
    const u16* __restrict__ Abase, const u16* __restrict__ Btbase,
    const float* __restrict__ bias,
    u16* __restrict__ Hout, float* __restrict__ Out,
    const int* __restrict__ offsets, const int* __restrict__ perm,
    const float* __restrict__ pairw){
  constexpr int Kd = (EPI==0)?DDIM:HDIM;
  constexpr int Nn = (EPI==0)?HDIM:DDIM;
  constexpr int NT = Kd/64;          // K-tiles (16 or 64, pow2)
  constexpr int NIT = NT/2;          // 2 tiles per unrolled iteration
  constexpr int BR = 16, BC = Nn/256, PER_E = BR*BC, G = NEXP*PER_E;
  extern __shared__ __align__(16) char smem[];

  int bid = blockIdx.x;
  int lg = (bid&7)*(G/8) + (bid>>3);          // XCD-bijective (G%8==0)
  int e = lg/PER_E, r = lg%PER_E;
  int bcol = r/BR, brow = r%BR;               // brow inner: B-tile reuse
  int off = offsets[e], cnt = offsets[e+1]-off;
  if (brow*256 >= cnt) return;
  int lane = threadIdx.x&63, wid = (int)threadIdx.x>>6;
  int wr = wid>>2, wc = wid&3;                // 2x4 wave grid

  // ---- staging: linear LDS dest (chunk c = subtile c), pre-swizzled source --
  int l4 = lane>>2;
  int kof = (wid&1)*32 + (((lane&3)*8) ^ (((lane>>5)&1)*16));
  const u16* aS[2][2]; const u16* bS[2][2];
  #pragma unroll
  for (int h=0;h<2;h++)
    #pragma unroll
    for (int j=0;j<2;j++){
      int row = h*128 + ((wid>>1) + j*4)*16 + l4;
      aS[h][j] = Abase + (size_t)(off + min(brow*256+row, cnt-1))*Kd + kof;
      bS[h][j] = Btbase + (size_t)e*Nn*Kd + (size_t)(bcol*256+row)*Kd + kof;
    }
  char* ldsA = smem; char* ldsB = smem + 65536;
  int dst0 = wid*1024 + lane*16, dst1 = 8192 + wid*1024 + lane*16;

  // single-load stagers: D0 = half-rows 0-63, D1 = half-rows 64-127
#define STG_A_D0(h, tile, buf) \
    gload_lds16(aS[h][0]+(size_t)(tile)*64, ldsA+(buf)*32768+(h)*16384+dst0);
#define STG_A_D1(h, tile, buf) \
    gload_lds16(aS[h][1]+(size_t)(tile)*64, ldsA+(buf)*32768+(h)*16384+dst1);
#define STG_B(h, tile, buf) { \
    gload_lds16(bS[h][0]+(size_t)(tile)*64, ldsB+(buf)*32768+(h)*16384+dst0); \
    gload_lds16(bS[h][1]+(size_t)(tile)*64, ldsB+(buf)*32768+(h)*16384+dst1); }

  // ---- fragment reads (subtiled+swizzled ds_read_b128) ----
  int lr = lane&15;
  int rdq = lr*64 + (((lane>>4)*16) ^ (((lane>>3)&1)<<5));
  const char* aRd = ldsA + wr*16384;           // wave's A half
  const char* bRd = ldsB + (wc>>1)*16384;      // wave's B half
  f16x8 a[4][2], b[2][2][2];
  f32x4 acc[8][4] = {};

#define RD_A(mh, buf) { _Pragma("unroll") for (int mf=0;mf<4;mf++) \
    _Pragma("unroll") for (int ks=0;ks<2;ks++) \
      a[mf][ks] = *(const f16x8*)(aRd + (buf)*32768 + \
        (mh)*8192 + mf*2048 + ks*1024 + rdq); }
#define RD_B(np, buf) { _Pragma("unroll") for (int nf=0;nf<2;nf++) \
    _Pragma("unroll") for (int ks=0;ks<2;ks++) \
      b[np][nf][ks] = *(const f16x8*)(bRd + (buf)*32768 + \
        (wc&1)*8192 + ((np)*2+nf)*2048 + ks*1024 + rdq); }
#define MM(mh, np) { _Pragma("unroll") for (int mf=0;mf<4;mf++) \
    _Pragma("unroll") for (int nf=0;nf<2;nf++) \
    _Pragma("unroll") for (int ks=0;ks<2;ks++) \
      acc[(mh)*4+mf][(np)*2+nf] = __builtin_amdgcn_mfma_f32_16x16x32_f16( \
        a[mf][ks], b[np][nf][ks], acc[(mh)*4+mf][(np)*2+nf], 0,0,0); }

#define BAR   __builtin_amdgcn_s_barrier()
#define LGKM0 { asm volatile("s_waitcnt lgkmcnt(0)" ::: "memory"); \
                __builtin_amdgcn_sched_barrier(0); }
#define VM6   { asm volatile("s_waitcnt vmcnt(6)" ::: "memory"); \
                __builtin_amdgcn_sched_barrier(0); }
#define VM0   { asm volatile("s_waitcnt vmcnt(0)" ::: "memory"); \
                __builtin_amdgcn_sched_barrier(0); }
#define PRIO1 __builtin_amdgcn_s_setprio(1)
#define PRIO0 __builtin_amdgcn_s_setprio(0)

  // prologue: tile0 full -> buf0 (8 loads); {A-dst0,B0,B1}(tile1) -> buf1 (6).
  // VM6 retires tile0's 8, leaves tile1's 6 in flight == steady state.
  STG_A_D0(0,0,0); STG_A_D1(0,0,0); STG_A_D0(1,0,0); STG_A_D1(1,0,0);
  STG_B(0,0,0); STG_B(1,0,0);
  STG_A_D0(0,1,1); STG_A_D0(1,1,1); STG_B(0,1,1); STG_B(1,1,1);
  VM6; BAR;

  for (int it=0; it<NIT; ++it){
    int T0 = 2*it;
    int u1 = (T0+1)&(NT-1), u2 = (T0+2)&(NT-1);   // group A targets
    int v2 = (T0+3)&(NT-1);                        // group B far target
    // group A: compute tile T0 (buf0)
    RD_A(0,0); RD_B(0,0); STG_A_D1(0,u1,1); STG_A_D1(1,u1,1);
                                     BAR; LGKM0; PRIO1; MM(0,0); PRIO0; BAR;
    RD_B(1,0);            STG_A_D0(0,u2,0); STG_A_D0(1,u2,0);
                                     BAR; LGKM0; PRIO1; MM(0,1); PRIO0; BAR;
    RD_A(1,0);            STG_B(0,u2,0);
                                     BAR; LGKM0; PRIO1; MM(1,1); PRIO0; BAR;
                          STG_B(1,u2,0);
                                     BAR;        PRIO1; MM(1,0); PRIO0; VM6; BAR;
    // group B: compute tile T0+1 (buf1)
    RD_A(0,1); RD_B(0,1); STG_A_D1(0,u2,0); STG_A_D1(1,u2,0);
                                     BAR; LGKM0; PRIO1; MM(0,0); PRIO0; BAR;
    RD_B(1,1);            STG_A_D0(0,v2,1); STG_A_D0(1,v2,1);
                                     BAR; LGKM0; PRIO1; MM(0,1); PRIO0; BAR;
    RD_A(1,1);            STG_B(0,v2,1);
                                     BAR; LGKM0; PRIO1; MM(1,1); PRIO0; BAR;
                          STG_B(1,v2,1);
                                     BAR;        PRIO1; MM(1,0); PRIO0; VM6; BAR;
  }
  VM0;   // drain in-flight LDS writes before block exit

  // epilogue: C row = brow*256 + wr*128 + am*16 + (lane>>4)*4 + j
  //           C col = bcol*256 + wc*64 + an*16 + (lane&15)
  int lr4 = (lane>>4)*4, lc = lane&15;
  #pragma unroll
  for (int am=0;am<8;am++){
    #pragma unroll
    for (int j=0;j<4;j++){
      int grow = brow*256 + wr*128 + am*16 + lr4 + j;
      if (grow < cnt){
        int p = off + grow;
        if (EPI==0){
          size_t rbase = (size_t)p*Nn;
          #pragma unroll
          for (int an=0;an<4;an++){
            int colg = bcol*256 + wc*64 + an*16 + lc;
            float v = acc[am][an][j] + bias[e*Nn + colg];
            Hout[rbase + colg] = f2h_bits(gelu_tanh(v));
          }
        } else {
          int tok = perm[p]; float wv = pairw[p];
          size_t obase = (size_t)tok*Nn;
          #pragma unroll
          for (int an=0;an<4;an++){
            int colg = bcol*256 + wc*64 + an*16 + lc;
            atomicAdd(&Out[obase + colg], wv*(acc[am][an][j] + bias[e*Nn + colg]));
          }
        }
      }
    }
  }
#undef STG_A_D0
#undef STG_A_D1
#undef STG_B
#undef RD_A
#undef RD_B
#undef MM
#undef BAR
#undef LGKM0
#undef VM6
#undef VM0
#undef PRIO1
#undef PRIO0
}

extern "C" void kernel_launch(void* const* d_in, const int* in_sizes, int n_in,
                              void* d_out, int out_size, void* d_ws, size_t ws_size,
                              hipStream_t stream){
  const float* x  = (const float*)d_in[0];
  const float* gw = (const float*)d_in[1];
  const float* gb = (const float*)d_in[2];
  const float* w1 = (const float*)d_in[3];
  const float* b1 = (const float*)d_in[4];
  const float* w2 = (const float*)d_in[5];
  const float* b2 = (const float*)d_in[6];
  float* out = (float*)d_out;
  char* ws = (char*)d_ws;

  // workspace layout
  int*   offsets = (int*)(ws + 64);
  int*   tok_e   = (int*)(ws + 256);
  float* tok_w   = (float*)(ws + 256 + 1*65536);
  int*   perm    = (int*)(ws + 256 + 2*65536);
  float* pairw   = (float*)(ws + 256 + 3*65536);
  size_t base = 256 + 4*65536;
  u16* xg   = (u16*)(ws + base);                                     // 32 MiB
  u16* w1t  = (u16*)(ws + base + 33554432ull);                       // 64 MiB
  u16* w2t  = (u16*)(ws + base + 33554432ull + 67108864ull);         // 64 MiB
  u16* hbuf = (u16*)(ws + base + 33554432ull + 2*67108864ull);       // 128 MiB
  size_t need = base + 33554432ull + 2*67108864ull + 134217728ull;

  hipMemsetAsync(d_out, 0, (size_t)out_size*sizeof(float), stream);
  if (ws_size < need) return;   // graceful fail: zeros out

  hipFuncSetAttribute(reinterpret_cast<const void*>(moe_gemm8<0>),
                      hipFuncAttributeMaxDynamicSharedMemorySize, 131072);
  hipFuncSetAttribute(reinterpret_cast<const void*>(moe_gemm8<1>),
                      hipFuncAttributeMaxDynamicSharedMemorySize, 131072);

  gate_kernel<<<N_TOK/4, 256, 0, stream>>>(x, gw, gb, tok_e, tok_w);
  rank_kernel<<<1, 1024, 0, stream>>>(tok_e, tok_w, offsets, perm, pairw);
  build_gather_kernel<<<NPAIR/4, 256, 0, stream>>>(x, perm, xg);
  transpose_convert_kernel<<<dim3(HDIM/64, DDIM/64, NEXP), 256, 0, stream>>>(w1, w1t, DDIM, HDIM);
  transpose_convert_kernel<<<dim3(DDIM/64, HDIM/64, NEXP), 256, 0, stream>>>(w2, w2t, HDIM, DDIM);
  moe_gemm8<0><<<NEXP*16*(HDIM/256), 512, 131072, stream>>>(
      xg, w1t, b1, hbuf, nullptr, offsets, perm, pairw);
  moe_gemm8<1><<<NEXP*16*(DDIM/256), 512, 131072, stream>>>(
      hbuf, w2t, b2, nullptr, out, offsets, perm, pairw);
}

// Round 7
// 642.491 us; speedup vs baseline: 1.5612x; 1.0845x over previous
//
#include <hip/hip_runtime.h>
#include <hip/hip_fp16.h>

#define N_TOK 8192
#define DDIM  1024
#define HDIM  4096
#define NEXP  8
#define NPAIR (N_TOK*2)

typedef unsigned short u16;
typedef _Float16 f16x8 __attribute__((ext_vector_type(8)));
typedef float    f32x4 __attribute__((ext_vector_type(4)));
typedef unsigned short u16x8 __attribute__((ext_vector_type(8)));

__device__ inline u16 f2h_bits(float f){
  _Float16 h = (_Float16)f;
  return __builtin_bit_cast(unsigned short, h);
}

typedef const __attribute__((address_space(1))) void* gas1_cvp;
typedef       __attribute__((address_space(3))) void* gas3_vp;
__device__ inline void gload_lds16(const void* g, void* l){
  __builtin_amdgcn_global_load_lds((gas1_cvp)g, (gas3_vp)l, 16, 0, 0);
}

// ---------------- gating: logits -> top2 + softmax (no atomics) ------------
__global__ __launch_bounds__(256) void gate_kernel(
    const float* __restrict__ x, const float* __restrict__ gw, const float* __restrict__ gb,
    int* __restrict__ tok_e, float* __restrict__ tok_w){
  int tok  = (int)((blockIdx.x*256u + threadIdx.x) >> 6);
  int lane = threadIdx.x & 63;
  if (tok >= N_TOK) return;
  const float* xr = x + (size_t)tok*DDIM;
  float acc[NEXP];
  #pragma unroll
  for (int e=0;e<NEXP;e++) acc[e]=0.f;
  for (int d=lane; d<DDIM; d+=64){
    float xv = xr[d];
    const float4* g4 = reinterpret_cast<const float4*>(gw + (size_t)d*NEXP);
    float4 a=g4[0], b=g4[1];
    acc[0]=fmaf(xv,a.x,acc[0]); acc[1]=fmaf(xv,a.y,acc[1]);
    acc[2]=fmaf(xv,a.z,acc[2]); acc[3]=fmaf(xv,a.w,acc[3]);
    acc[4]=fmaf(xv,b.x,acc[4]); acc[5]=fmaf(xv,b.y,acc[5]);
    acc[6]=fmaf(xv,b.z,acc[6]); acc[7]=fmaf(xv,b.w,acc[7]);
  }
  #pragma unroll
  for (int s=32;s>0;s>>=1)
    #pragma unroll
    for (int e=0;e<NEXP;e++) acc[e] += __shfl_xor(acc[e], s, 64);
  if (lane==0){
    #pragma unroll
    for (int e=0;e<NEXP;e++) acc[e]+=gb[e];
    int e0=0;
    #pragma unroll
    for (int e=1;e<NEXP;e++) if (acc[e]>acc[e0]) e0=e;   // strict >: ties -> lower idx
    int e1 = (e0==0)?1:0;
    #pragma unroll
    for (int e=0;e<NEXP;e++) if (e!=e0 && acc[e]>acc[e1]) e1=e;
    float p1 = 1.f/(1.f+__expf(acc[e0]-acc[e1]));        // softmax over top2
    float p0 = 1.f-p1;
    tok_e[tok*2]=e0; tok_e[tok*2+1]=e1;
    tok_w[tok*2]=p0; tok_w[tok*2+1]=p1;
  }
}

// ------ rank: deterministic expert-sorted positions via 1-block scan -------
__global__ __launch_bounds__(1024) void rank_kernel(
    const int* __restrict__ tok_e, const float* __restrict__ tok_w,
    int* __restrict__ offsets, int* __restrict__ perm, float* __restrict__ pairw){
  __shared__ u16 hist[NEXP][1024];
  __shared__ int expo[NEXP+1];
  int t = threadIdx.x;
  int c[NEXP];
  #pragma unroll
  for (int e=0;e<NEXP;e++) c[e]=0;
  int base = t*16;
  int le[16];
  #pragma unroll
  for (int i=0;i<16;i++){ le[i]=tok_e[base+i]; c[le[i]]++; }
  #pragma unroll
  for (int e=0;e<NEXP;e++) hist[e][t]=(u16)c[e];
  __syncthreads();
  for (int s=1; s<1024; s<<=1){
    u16 add[NEXP];
    #pragma unroll
    for (int e=0;e<NEXP;e++) add[e] = (t>=s)? hist[e][t-s] : (u16)0;
    __syncthreads();
    #pragma unroll
    for (int e=0;e<NEXP;e++) hist[e][t] += add[e];
    __syncthreads();
  }
  if (t==0){
    int s=0;
    #pragma unroll
    for (int e=0;e<NEXP;e++){ expo[e]=s; s+=hist[e][1023]; }
    expo[NEXP]=s;
    #pragma unroll
    for (int e=0;e<=NEXP;e++) offsets[e]=expo[e];
  }
  __syncthreads();
  int pos[NEXP];
  #pragma unroll
  for (int e=0;e<NEXP;e++) pos[e] = expo[e] + (int)hist[e][t] - c[e];
  #pragma unroll
  for (int i=0;i<16;i++){
    int e=le[i]; int p=pos[e]++;
    perm[p]=(base+i)>>1; pairw[p]=tok_w[base+i];
  }
}

// ------- gather token rows (fp32 -> fp16, expert-sorted, no atomics) -------
__global__ __launch_bounds__(256) void build_gather_kernel(
    const float* __restrict__ x, const int* __restrict__ perm, u16* __restrict__ xg){
  int pos  = (int)((blockIdx.x*256u + threadIdx.x) >> 6);
  int lane = threadIdx.x & 63;
  if (pos >= NPAIR) return;
  int tok = perm[pos];
  const float4* src = reinterpret_cast<const float4*>(x + (size_t)tok*DDIM);
  u16* dst = xg + (size_t)pos*DDIM;
  #pragma unroll
  for (int i=0;i<4;i++){
    float4 v = src[i*64+lane];
    ushort4 o;
    o.x=f2h_bits(v.x); o.y=f2h_bits(v.y); o.z=f2h_bits(v.z); o.w=f2h_bits(v.w);
    *reinterpret_cast<ushort4*>(dst + (size_t)(i*64+lane)*4) = o;
  }
}

// ------- transpose + convert: src fp32 [E][R][C] -> dst fp16 [E][C][R] -----
__global__ __launch_bounds__(256) void transpose_convert_kernel(
    const float* __restrict__ src, u16* __restrict__ dst, int R, int C){
  __shared__ float tile[64][65];
  int e = blockIdx.z;
  const float* s = src + (size_t)e*R*C;
  u16* d = dst + (size_t)e*R*C;
  int c0 = blockIdx.x*64, r0 = blockIdx.y*64;
  int t = threadIdx.x;
  int col4 = (t & 15) * 4, rrow = t >> 4;
  #pragma unroll
  for (int i=0;i<4;i++){
    int row = i*16 + rrow;
    float4 v = *reinterpret_cast<const float4*>(&s[(size_t)(r0+row)*C + c0 + col4]);
    tile[row][col4+0]=v.x; tile[row][col4+1]=v.y;
    tile[row][col4+2]=v.z; tile[row][col4+3]=v.w;
  }
  __syncthreads();
  int cIdx0 = t >> 3, r8 = (t & 7) * 8;
  #pragma unroll
  for (int j=0;j<2;j++){
    int c = j*32 + cIdx0;
    u16x8 o;
    #pragma unroll
    for (int u=0;u<8;u++) o[u] = f2h_bits(tile[r8+u][c]);
    *reinterpret_cast<u16x8*>(&d[(size_t)(c0+c)*R + r0 + r8]) = o;
  }
}

__device__ inline float gelu_tanh(float x){
  float u = 0.7978845608028654f*(x + 0.044715f*x*x*x);
  u = fminf(fmaxf(u,-9.f),9.f);
  float e2 = __expf(2.f*u);
  return 0.5f*x*(1.f + (e2-1.f)/(e2+1.f));
}

// ================= 128x128 segment GEMM, m97 structure =====================
// BK=32, 4 waves (2x2, per-wave 64x64), 32KB double-buffered LDS -> 3 blocks
// per CU (TLP covers the per-K-step barrier drain). Loop: stage-first into
// buf^1, ds_read buf, 16 MFMA, one __syncthreads (compiler emits the
// vmcnt/lgkmcnt drain). LDS per 8KB tile = 8 subtiles [16 rows][32 k] with
// the R4-verified XOR swizzle: addr(r,k)=(r>>4)*1024+(r&15)*64+((2k)^((r>>3&1)<<5)).
// Staged with linear gload_lds dest + inverse-permuted global source.
template<int EPI>
__global__ __launch_bounds__(256,3) void moe_gemm97(
    const u16* __restrict__ Abase, const u16* __restrict__ Btbase,
    const float* __restrict__ bias,
    u16* __restrict__ Hout, float* __restrict__ Out,
    const int* __restrict__ offsets, const int* __restrict__ perm,
    const float* __restrict__ pairw){
  constexpr int Kd = (EPI==0)?DDIM:HDIM;
  constexpr int Nn = (EPI==0)?HDIM:DDIM;
  constexpr int NT = Kd/32;          // K-steps
  constexpr int BR = 32, BC = Nn/128, PER_E = BR*BC, G = NEXP*PER_E;
  __shared__ __align__(16) char lds[32768];   // [buf][A 8KB | B 8KB]

  int bid = blockIdx.x;
  int lg = (bid&7)*(G/8) + (bid>>3);          // XCD-bijective (G%8==0)
  int e = lg/PER_E, r = lg%PER_E;
  int bcol = r/BR, brow = r%BR;               // brow inner: B-tile L2 reuse
  int off = offsets[e], cnt = offsets[e+1]-off;
  if (brow*128 >= cnt) return;
  int lane = threadIdx.x&63, wid = (int)threadIdx.x>>6;
  int wr = wid>>1, wc = wid&1;                // 2x2 wave grid

  // staging: chunks c = wid, wid+4; row = c*16 + lane>>2,
  // kelem = (lane&3)*8 ^ ((lane>>5)&1)*16  (inverse of the LDS swizzle)
  int l4 = lane>>2;
  int kof = ((lane&3)*8) ^ (((lane>>5)&1)*16);
  int row0 = wid*16 + l4, row1 = (wid+4)*16 + l4;
  const u16* BtE = Btbase + (size_t)e*Nn*Kd;
  const u16* aP0 = Abase + (size_t)(off + min(brow*128+row0, cnt-1))*Kd + kof;
  const u16* aP1 = Abase + (size_t)(off + min(brow*128+row1, cnt-1))*Kd + kof;
  const u16* bP0 = BtE + (size_t)(bcol*128+row0)*Kd + kof;
  const u16* bP1 = BtE + (size_t)(bcol*128+row1)*Kd + kof;
  int dst0 = wid*1024 + lane*16, dst1 = (wid+4)*1024 + lane*16;

#define STG(buf, t) { \
    gload_lds16(aP0 + (size_t)(t)*32, lds + (buf)*16384 + dst0); \
    gload_lds16(aP1 + (size_t)(t)*32, lds + (buf)*16384 + dst1); \
    gload_lds16(bP0 + (size_t)(t)*32, lds + (buf)*16384 + 8192 + dst0); \
    gload_lds16(bP1 + (size_t)(t)*32, lds + (buf)*16384 + 8192 + dst1); }

  // fragment reads: subtile st, byte rdq within it (conflict-free, R4-verified)
  int lr = lane&15;
  int rdq = lr*64 + (((lane>>4)*16) ^ (((lane>>3)&1)<<5));
  f32x4 acc[4][4] = {};

  STG(0, 0);
  __syncthreads();
  int buf = 0;
  for (int t=0; t<NT; ++t){
    if (t+1 < NT) STG(buf^1, t+1);
    const char* base = lds + buf*16384;
    f16x8 a[4], b[4];
    #pragma unroll
    for (int mf=0;mf<4;mf++)
      a[mf] = *reinterpret_cast<const f16x8*>(base + (wr*4+mf)*1024 + rdq);
    #pragma unroll
    for (int nf=0;nf<4;nf++)
      b[nf] = *reinterpret_cast<const f16x8*>(base + 8192 + (wc*4+nf)*1024 + rdq);
    #pragma unroll
    for (int mf=0;mf<4;mf++)
      #pragma unroll
      for (int nf=0;nf<4;nf++)
        acc[mf][nf] = __builtin_amdgcn_mfma_f32_16x16x32_f16(a[mf], b[nf], acc[mf][nf], 0,0,0);
    __syncthreads();      // compiler drains vmcnt (stage) + lgkm before barrier
    buf ^= 1;
  }
#undef STG

  // epilogue: C row = brow*128 + wr*64 + mf*16 + (lane>>4)*4 + j
  //           C col = bcol*128 + wc*64 + nf*16 + (lane&15)
  int lr4 = (lane>>4)*4, lc = lane&15;
  #pragma unroll
  for (int mf=0;mf<4;mf++){
    #pragma unroll
    for (int j=0;j<4;j++){
      int grow = brow*128 + wr*64 + mf*16 + lr4 + j;
      if (grow < cnt){
        int p = off + grow;
        if (EPI==0){
          size_t rbase = (size_t)p*Nn;
          #pragma unroll
          for (int nf=0;nf<4;nf++){
            int colg = bcol*128 + wc*64 + nf*16 + lc;
            float v = acc[mf][nf][j] + bias[e*Nn + colg];
            Hout[rbase + colg] = f2h_bits(gelu_tanh(v));
          }
        } else {
          int tok = perm[p]; float wv = pairw[p];
          size_t obase = (size_t)tok*Nn;
          #pragma unroll
          for (int nf=0;nf<4;nf++){
            int colg = bcol*128 + wc*64 + nf*16 + lc;
            atomicAdd(&Out[obase + colg], wv*(acc[mf][nf][j] + bias[e*Nn + colg]));
          }
        }
      }
    }
  }
}

extern "C" void kernel_launch(void* const* d_in, const int* in_sizes, int n_in,
                              void* d_out, int out_size, void* d_ws, size_t ws_size,
                              hipStream_t stream){
  const float* x  = (const float*)d_in[0];
  const float* gw = (const float*)d_in[1];
  const float* gb = (const float*)d_in[2];
  const float* w1 = (const float*)d_in[3];
  const float* b1 = (const float*)d_in[4];
  const float* w2 = (const float*)d_in[5];
  const float* b2 = (const float*)d_in[6];
  float* out = (float*)d_out;
  char* ws = (char*)d_ws;

  // workspace layout
  int*   offsets = (int*)(ws + 64);
  int*   tok_e   = (int*)(ws + 256);
  float* tok_w   = (float*)(ws + 256 + 1*65536);
  int*   perm    = (int*)(ws + 256 + 2*65536);
  float* pairw   = (float*)(ws + 256 + 3*65536);
  size_t base = 256 + 4*65536;
  u16* xg   = (u16*)(ws + base);                                     // 32 MiB
  u16* w1t  = (u16*)(ws + base + 33554432ull);                       // 64 MiB
  u16* w2t  = (u16*)(ws + base + 33554432ull + 67108864ull);         // 64 MiB
  u16* hbuf = (u16*)(ws + base + 33554432ull + 2*67108864ull);       // 128 MiB
  size_t need = base + 33554432ull + 2*67108864ull + 134217728ull;

  hipMemsetAsync(d_out, 0, (size_t)out_size*sizeof(float), stream);
  if (ws_size < need) return;   // graceful fail: zeros out

  gate_kernel<<<N_TOK/4, 256, 0, stream>>>(x, gw, gb, tok_e, tok_w);
  rank_kernel<<<1, 1024, 0, stream>>>(tok_e, tok_w, offsets, perm, pairw);
  build_gather_kernel<<<NPAIR/4, 256, 0, stream>>>(x, perm, xg);
  transpose_convert_kernel<<<dim3(HDIM/64, DDIM/64, NEXP), 256, 0, stream>>>(w1, w1t, DDIM, HDIM);
  transpose_convert_kernel<<<dim3(DDIM/64, HDIM/64, NEXP), 256, 0, stream>>>(w2, w2t, HDIM, DDIM);
  moe_gemm97<0><<<NEXP*32*(HDIM/128), 256, 0, stream>>>(
      xg, w1t, b1, hbuf, nullptr, offsets, perm, pairw);
  moe_gemm97<1><<<NEXP*32*(DDIM/128), 256, 0, stream>>>(
      hbuf, w2t, b2, nullptr, out, offsets, perm, pairw);
}

// Round 8
// 580.410 us; speedup vs baseline: 1.7282x; 1.1070x over previous
//
#include <hip/hip_runtime.h>
#include <hip/hip_fp16.h>

#define N_TOK 8192
#define DDIM  1024
#define HDIM  4096
#define NEXP  8
#define NPAIR (N_TOK*2)

typedef unsigned short u16;
typedef _Float16 f16x8 __attribute__((ext_vector_type(8)));
typedef float    f32x4 __attribute__((ext_vector_type(4)));
typedef unsigned short u16x8 __attribute__((ext_vector_type(8)));

__device__ inline u16 f2h_bits(float f){
  _Float16 h = (_Float16)f;
  return __builtin_bit_cast(unsigned short, h);
}
__device__ inline float h2f(u16 b){
  _Float16 h = __builtin_bit_cast(_Float16, b);
  return (float)h;
}

typedef const __attribute__((address_space(1))) void* gas1_cvp;
typedef       __attribute__((address_space(3))) void* gas3_vp;
__device__ inline void gload_lds16(const void* g, void* l){
  __builtin_amdgcn_global_load_lds((gas1_cvp)g, (gas3_vp)l, 16, 0, 0);
}

// ---------------- gating: logits -> top2 + softmax (no atomics) ------------
__global__ __launch_bounds__(256) void gate_kernel(
    const float* __restrict__ x, const float* __restrict__ gw, const float* __restrict__ gb,
    int* __restrict__ tok_e, float* __restrict__ tok_w){
  int tok  = (int)((blockIdx.x*256u + threadIdx.x) >> 6);
  int lane = threadIdx.x & 63;
  if (tok >= N_TOK) return;
  const float* xr = x + (size_t)tok*DDIM;
  float acc[NEXP];
  #pragma unroll
  for (int e=0;e<NEXP;e++) acc[e]=0.f;
  for (int d=lane; d<DDIM; d+=64){
    float xv = xr[d];
    const float4* g4 = reinterpret_cast<const float4*>(gw + (size_t)d*NEXP);
    float4 a=g4[0], b=g4[1];
    acc[0]=fmaf(xv,a.x,acc[0]); acc[1]=fmaf(xv,a.y,acc[1]);
    acc[2]=fmaf(xv,a.z,acc[2]); acc[3]=fmaf(xv,a.w,acc[3]);
    acc[4]=fmaf(xv,b.x,acc[4]); acc[5]=fmaf(xv,b.y,acc[5]);
    acc[6]=fmaf(xv,b.z,acc[6]); acc[7]=fmaf(xv,b.w,acc[7]);
  }
  #pragma unroll
  for (int s=32;s>0;s>>=1)
    #pragma unroll
    for (int e=0;e<NEXP;e++) acc[e] += __shfl_xor(acc[e], s, 64);
  if (lane==0){
    #pragma unroll
    for (int e=0;e<NEXP;e++) acc[e]+=gb[e];
    int e0=0;
    #pragma unroll
    for (int e=1;e<NEXP;e++) if (acc[e]>acc[e0]) e0=e;   // strict >: ties -> lower idx
    int e1 = (e0==0)?1:0;
    #pragma unroll
    for (int e=0;e<NEXP;e++) if (e!=e0 && acc[e]>acc[e1]) e1=e;
    float p1 = 1.f/(1.f+__expf(acc[e0]-acc[e1]));        // softmax over top2
    float p0 = 1.f-p1;
    tok_e[tok*2]=e0; tok_e[tok*2+1]=e1;
    tok_w[tok*2]=p0; tok_w[tok*2+1]=p1;
  }
}

// ------ rank: deterministic expert-sorted positions via 1-block scan -------
__global__ __launch_bounds__(1024) void rank_kernel(
    const int* __restrict__ tok_e, const float* __restrict__ tok_w,
    int* __restrict__ offsets, int* __restrict__ perm, float* __restrict__ pairw,
    int* __restrict__ pospair){
  __shared__ u16 hist[NEXP][1024];
  __shared__ int expo[NEXP+1];
  int t = threadIdx.x;
  int c[NEXP];
  #pragma unroll
  for (int e=0;e<NEXP;e++) c[e]=0;
  int base = t*16;
  int le[16];
  #pragma unroll
  for (int i=0;i<16;i++){ le[i]=tok_e[base+i]; c[le[i]]++; }
  #pragma unroll
  for (int e=0;e<NEXP;e++) hist[e][t]=(u16)c[e];
  __syncthreads();
  for (int s=1; s<1024; s<<=1){
    u16 add[NEXP];
    #pragma unroll
    for (int e=0;e<NEXP;e++) add[e] = (t>=s)? hist[e][t-s] : (u16)0;
    __syncthreads();
    #pragma unroll
    for (int e=0;e<NEXP;e++) hist[e][t] += add[e];
    __syncthreads();
  }
  if (t==0){
    int s=0;
    #pragma unroll
    for (int e=0;e<NEXP;e++){ expo[e]=s; s+=hist[e][1023]; }
    expo[NEXP]=s;
    #pragma unroll
    for (int e=0;e<=NEXP;e++) offsets[e]=expo[e];
  }
  __syncthreads();
  int pos[NEXP];
  #pragma unroll
  for (int e=0;e<NEXP;e++) pos[e] = expo[e] + (int)hist[e][t] - c[e];
  #pragma unroll
  for (int i=0;i<16;i++){
    int e=le[i]; int p=pos[e]++;
    perm[p]=(base+i)>>1; pairw[p]=tok_w[base+i]; pospair[base+i]=p;
  }
}

// ------- gather token rows (fp32 -> fp16, expert-sorted, no atomics) -------
__global__ __launch_bounds__(256) void build_gather_kernel(
    const float* __restrict__ x, const int* __restrict__ perm, u16* __restrict__ xg){
  int pos  = (int)((blockIdx.x*256u + threadIdx.x) >> 6);
  int lane = threadIdx.x & 63;
  if (pos >= NPAIR) return;
  int tok = perm[pos];
  const float4* src = reinterpret_cast<const float4*>(x + (size_t)tok*DDIM);
  u16* dst = xg + (size_t)pos*DDIM;
  #pragma unroll
  for (int i=0;i<4;i++){
    float4 v = src[i*64+lane];
    ushort4 o;
    o.x=f2h_bits(v.x); o.y=f2h_bits(v.y); o.z=f2h_bits(v.z); o.w=f2h_bits(v.w);
    *reinterpret_cast<ushort4*>(dst + (size_t)(i*64+lane)*4) = o;
  }
}

// ------- transpose + convert: src fp32 [E][R][C] -> dst fp16 [E][C][R] -----
__global__ __launch_bounds__(256) void transpose_convert_kernel(
    const float* __restrict__ src, u16* __restrict__ dst, int R, int C){
  __shared__ float tile[64][65];
  int e = blockIdx.z;
  const float* s = src + (size_t)e*R*C;
  u16* d = dst + (size_t)e*R*C;
  int c0 = blockIdx.x*64, r0 = blockIdx.y*64;
  int t = threadIdx.x;
  int col4 = (t & 15) * 4, rrow = t >> 4;
  #pragma unroll
  for (int i=0;i<4;i++){
    int row = i*16 + rrow;
    float4 v = *reinterpret_cast<const float4*>(&s[(size_t)(r0+row)*C + c0 + col4]);
    tile[row][col4+0]=v.x; tile[row][col4+1]=v.y;
    tile[row][col4+2]=v.z; tile[row][col4+3]=v.w;
  }
  __syncthreads();
  int cIdx0 = t >> 3, r8 = (t & 7) * 8;
  #pragma unroll
  for (int j=0;j<2;j++){
    int c = j*32 + cIdx0;
    u16x8 o;
    #pragma unroll
    for (int u=0;u<8;u++) o[u] = f2h_bits(tile[r8+u][c]);
    *reinterpret_cast<u16x8*>(&d[(size_t)(c0+c)*R + r0 + r8]) = o;
  }
}

__device__ inline float gelu_tanh(float x){
  float u = 0.7978845608028654f*(x + 0.044715f*x*x*x);
  u = fminf(fmaxf(u,-9.f),9.f);
  float e2 = __expf(2.f*u);
  return 0.5f*x*(1.f + (e2-1.f)/(e2+1.f));
}

// ---------- combine: out[tok] = ybuf[pos(2tok)] + ybuf[pos(2tok+1)] --------
__global__ __launch_bounds__(256) void combine_kernel(
    const u16* __restrict__ ybuf, const int* __restrict__ pospair,
    float* __restrict__ out){
  int tok  = (int)((blockIdx.x*256u + threadIdx.x) >> 6);
  int lane = threadIdx.x & 63;
  if (tok >= N_TOK) return;
  int p0 = pospair[tok*2], p1 = pospair[tok*2+1];
  const u16x8* y0 = reinterpret_cast<const u16x8*>(ybuf + (size_t)p0*DDIM);
  const u16x8* y1 = reinterpret_cast<const u16x8*>(ybuf + (size_t)p1*DDIM);
  float4* o = reinterpret_cast<float4*>(out + (size_t)tok*DDIM);
  #pragma unroll
  for (int i=0;i<2;i++){
    u16x8 a8 = y0[i*64+lane], b8 = y1[i*64+lane];
    float4 r0, r1;
    #pragma unroll
    for (int j=0;j<4;j++){
      r0[j] = h2f(a8[j])   + h2f(b8[j]);
      r1[j] = h2f(a8[4+j]) + h2f(b8[4+j]);
    }
    o[(i*64+lane)*2]   = r0;
    o[(i*64+lane)*2+1] = r1;
  }
}

// ================= 128x128 segment GEMM, m97 structure =====================
// BK=32, 4 waves (2x2, per-wave 64x64), 32KB double-buffered LDS, 4 blocks/CU.
// SWAPPED MFMA operands: acc[mf][nf] = mfma(b[nf], a[mf], acc) so per-thread
// reg j = 4 consecutive N-cols (m89 C-layout: "col"=lane&15 -> M row,
// "row"=(lane>>4)*4+j -> N col). Epilogue: float4 bias + 8B ushort4 stores.
// EPI 0: h = gelu(acc+b1) -> Hout fp16. EPI 1: ybuf[p] = wv*(acc+b2) fp16.
template<int EPI>
__global__ __launch_bounds__(256,4) void moe_gemm97(
    const u16* __restrict__ Abase, const u16* __restrict__ Btbase,
    const float* __restrict__ bias,
    u16* __restrict__ Hout, u16* __restrict__ Ybuf,
    const int* __restrict__ offsets, const float* __restrict__ pairw){
  constexpr int Kd = (EPI==0)?DDIM:HDIM;
  constexpr int Nn = (EPI==0)?HDIM:DDIM;
  constexpr int NT = Kd/32;          // K-steps
  constexpr int BR = 32, BC = Nn/128, PER_E = BR*BC, G = NEXP*PER_E;
  __shared__ __align__(16) char lds[32768];   // [buf][A 8KB | B 8KB]

  int bid = blockIdx.x;
  int lg = (bid&7)*(G/8) + (bid>>3);          // XCD-bijective (G%8==0)
  int e = lg/PER_E, r = lg%PER_E;
  int bcol = r/BR, brow = r%BR;               // brow inner: B-tile L2 reuse
  int off = offsets[e], cnt = offsets[e+1]-off;
  if (brow*128 >= cnt) return;
  int lane = threadIdx.x&63, wid = (int)threadIdx.x>>6;
  int wr = wid>>1, wc = wid&1;                // 2x2 wave grid

  // staging: chunks c = wid, wid+4; row = c*16 + lane>>2,
  // kelem = (lane&3)*8 ^ ((lane>>5)&1)*16  (inverse of the LDS swizzle)
  int l4 = lane>>2;
  int kof = ((lane&3)*8) ^ (((lane>>5)&1)*16);
  int row0 = wid*16 + l4, row1 = (wid+4)*16 + l4;
  const u16* BtE = Btbase + (size_t)e*Nn*Kd;
  const u16* aP0 = Abase + (size_t)(off + min(brow*128+row0, cnt-1))*Kd + kof;
  const u16* aP1 = Abase + (size_t)(off + min(brow*128+row1, cnt-1))*Kd + kof;
  const u16* bP0 = BtE + (size_t)(bcol*128+row0)*Kd + kof;
  const u16* bP1 = BtE + (size_t)(bcol*128+row1)*Kd + kof;
  int dst0 = wid*1024 + lane*16, dst1 = (wid+4)*1024 + lane*16;

#define STG(buf, t) { \
    gload_lds16(aP0 + (size_t)(t)*32, lds + (buf)*16384 + dst0); \
    gload_lds16(aP1 + (size_t)(t)*32, lds + (buf)*16384 + dst1); \
    gload_lds16(bP0 + (size_t)(t)*32, lds + (buf)*16384 + 8192 + dst0); \
    gload_lds16(bP1 + (size_t)(t)*32, lds + (buf)*16384 + 8192 + dst1); }

  // fragment reads (conflict-free subtile swizzle, R4-verified)
  int lr = lane&15;
  int rdq = lr*64 + (((lane>>4)*16) ^ (((lane>>3)&1)<<5));
  f32x4 acc[4][4] = {};

  STG(0, 0);
  __syncthreads();
  int buf = 0;
  for (int t=0; t<NT; ++t){
    if (t+1 < NT) STG(buf^1, t+1);
    const char* base = lds + buf*16384;
    f16x8 a[4], b[4];
    #pragma unroll
    for (int mf=0;mf<4;mf++)
      a[mf] = *reinterpret_cast<const f16x8*>(base + (wr*4+mf)*1024 + rdq);
    #pragma unroll
    for (int nf=0;nf<4;nf++)
      b[nf] = *reinterpret_cast<const f16x8*>(base + 8192 + (wc*4+nf)*1024 + rdq);
    #pragma unroll
    for (int mf=0;mf<4;mf++)
      #pragma unroll
      for (int nf=0;nf<4;nf++)
        acc[mf][nf] = __builtin_amdgcn_mfma_f32_16x16x32_f16(b[nf], a[mf], acc[mf][nf], 0,0,0);
    __syncthreads();      // compiler drains vmcnt (stage) + lgkm before barrier
    buf ^= 1;
  }
#undef STG

  // epilogue (swapped layout): row = brow*128+wr*64+mf*16+(lane&15)
  //   col quad = bcol*128+wc*64+nf*16+(lane>>4)*4 + j (j=0..3 contiguous)
  int lcq = (lane>>4)*4;
  #pragma unroll
  for (int mf=0;mf<4;mf++){
    int grow = brow*128 + wr*64 + mf*16 + lr;
    if (grow < cnt){
      int p = off + grow;
      size_t rbase = (size_t)p*Nn;
      float wv = (EPI==0) ? 0.f : pairw[p];
      #pragma unroll
      for (int nf=0;nf<4;nf++){
        int colg = bcol*128 + wc*64 + nf*16 + lcq;
        float4 bv = *reinterpret_cast<const float4*>(&bias[e*Nn + colg]);
        ushort4 o;
        if (EPI==0){
          o.x = f2h_bits(gelu_tanh(acc[mf][nf][0] + bv.x));
          o.y = f2h_bits(gelu_tanh(acc[mf][nf][1] + bv.y));
          o.z = f2h_bits(gelu_tanh(acc[mf][nf][2] + bv.z));
          o.w = f2h_bits(gelu_tanh(acc[mf][nf][3] + bv.w));
          *reinterpret_cast<ushort4*>(&Hout[rbase + colg]) = o;
        } else {
          o.x = f2h_bits(wv*(acc[mf][nf][0] + bv.x));
          o.y = f2h_bits(wv*(acc[mf][nf][1] + bv.y));
          o.z = f2h_bits(wv*(acc[mf][nf][2] + bv.z));
          o.w = f2h_bits(wv*(acc[mf][nf][3] + bv.w));
          *reinterpret_cast<ushort4*>(&Ybuf[rbase + colg]) = o;
        }
      }
    }
  }
}

extern "C" void kernel_launch(void* const* d_in, const int* in_sizes, int n_in,
                              void* d_out, int out_size, void* d_ws, size_t ws_size,
                              hipStream_t stream){
  const float* x  = (const float*)d_in[0];
  const float* gw = (const float*)d_in[1];
  const float* gb = (const float*)d_in[2];
  const float* w1 = (const float*)d_in[3];
  const float* b1 = (const float*)d_in[4];
  const float* w2 = (const float*)d_in[5];
  const float* b2 = (const float*)d_in[6];
  float* out = (float*)d_out;
  char* ws = (char*)d_ws;

  // workspace layout
  int*   offsets = (int*)(ws + 64);
  int*   tok_e   = (int*)(ws + 256);
  float* tok_w   = (float*)(ws + 256 + 1*65536);
  int*   perm    = (int*)(ws + 256 + 2*65536);
  float* pairw   = (float*)(ws + 256 + 3*65536);
  int*   pospair = (int*)(ws + 256 + 4*65536);
  size_t base = 256 + 5*65536;
  u16* xg   = (u16*)(ws + base);                                     // 32 MiB
  u16* w1t  = (u16*)(ws + base + 33554432ull);                       // 64 MiB
  u16* w2t  = (u16*)(ws + base + 33554432ull + 67108864ull);         // 64 MiB
  u16* hbuf = (u16*)(ws + base + 33554432ull + 2*67108864ull);       // 128 MiB
  u16* ybuf = xg;   // xg dead after GEMM1; reuse as per-pair output (32 MiB)
  size_t need = base + 33554432ull + 2*67108864ull + 134217728ull;

  if (ws_size < need){   // graceful fail: zeros out
    hipMemsetAsync(d_out, 0, (size_t)out_size*sizeof(float), stream);
    return;
  }

  gate_kernel<<<N_TOK/4, 256, 0, stream>>>(x, gw, gb, tok_e, tok_w);
  rank_kernel<<<1, 1024, 0, stream>>>(tok_e, tok_w, offsets, perm, pairw, pospair);
  build_gather_kernel<<<NPAIR/4, 256, 0, stream>>>(x, perm, xg);
  transpose_convert_kernel<<<dim3(HDIM/64, DDIM/64, NEXP), 256, 0, stream>>>(w1, w1t, DDIM, HDIM);
  transpose_convert_kernel<<<dim3(DDIM/64, HDIM/64, NEXP), 256, 0, stream>>>(w2, w2t, HDIM, DDIM);
  moe_gemm97<0><<<NEXP*32*(HDIM/128), 256, 0, stream>>>(
      xg, w1t, b1, hbuf, nullptr, offsets, pairw);
  moe_gemm97<1><<<NEXP*32*(DDIM/128), 256, 0, stream>>>(
      hbuf, w2t, b2, nullptr, ybuf, offsets, pairw);
  combine_kernel<<<N_TOK/4, 256, 0, stream>>>(ybuf, pospair, out);
}